// Round 5
// baseline (272.397 us; speedup 1.0000x reference)
//
#include <hip/hip_runtime.h>
#include <math.h>

// ---- problem constants ----
#define B_   2
#define T_   2048
#define D_   1024
#define H_   16
#define DH_  64
#define DC_  1024
#define DFF_ 1656
#define DFFP_ 1664
#define MTOT 4096          // B_*T_
#define NELEM_X 4194304ull // B*T*D

typedef short s16x8 __attribute__((ext_vector_type(8)));
typedef unsigned short u16x4 __attribute__((ext_vector_type(4)));
typedef float f32x4 __attribute__((ext_vector_type(4)));
typedef unsigned short bfbits;

__device__ __forceinline__ bfbits f2bf(float f) {
  unsigned int u = __builtin_bit_cast(unsigned int, f);
  u += 0x7fffu + ((u >> 16) & 1u);          // RNE
  return (bfbits)(u >> 16);
}

__device__ __forceinline__ float vexp2(float x) {   // 2^x via HW transcendental
  float r;
  asm("v_exp_f32 %0, %1" : "=v"(r) : "v"(x));
  return r;
}
__device__ __forceinline__ unsigned pkbf(float lo, float hi) { // 2xbf16 pack, RNE
  unsigned r;
  asm("v_cvt_pk_bf16_f32 %0, %1, %2" : "=v"(r) : "v"(lo), "v"(hi));
  return r;
}

__device__ __forceinline__ void gload16(const void* g, void* l) {
  __builtin_amdgcn_global_load_lds(
      (__attribute__((address_space(1))) void*)g,
      (__attribute__((address_space(3))) void*)l, 16, 0, 0);
}

// ---------- workspace offsets (bytes) ----------
constexpr size_t OFF_X1   = 0;                                  // f32 x1
constexpr size_t OFF_H    = OFF_X1 + 4ull*NELEM_X;              // bf16 h ; later h2
constexpr size_t OFF_Q    = OFF_H  + 2ull*NELEM_X;              // bf16 Q [BH][T][64] ; later ffmid
constexpr size_t OFF_K    = OFF_Q  + 2ull*NELEM_X;              // bf16 K [BH][T][64]
constexpr size_t OFF_VT   = OFF_K  + 2ull*NELEM_X;              // bf16 V^T [BH][64][T]
constexpr size_t OFF_AO   = OFF_VT + 2ull*NELEM_X;              // bf16 attn out [M][D]
constexpr size_t OFF_X2   = OFF_AO + 2ull*NELEM_X;              // f32 x2
constexpr size_t OFF_WQKV = OFF_X2 + 4ull*NELEM_X;              // bf16 [3072][1024]
constexpr size_t OFF_WO   = OFF_WQKV + 3072ull*1024*2;          // bf16 [1024][1024]
constexpr size_t OFF_WUP  = OFF_WO   + 1024ull*1024*2;          // bf16 [1664][1024]
constexpr size_t OFF_WDN  = OFF_WUP  + 1664ull*1024*2;          // bf16 [1024][1664]
constexpr size_t OFF_BVEC = OFF_WDN  + 1024ull*1664*2;          // f32 [B][D]
constexpr size_t OFF_CBV  = OFF_BVEC + 2048ull*4;               // f32 [B]
constexpr size_t OFF_GATE = OFF_CBV  + 256;                     // f32 [M]
constexpr size_t OFF_PART = OFF_GATE + 4096ull*4;               // f32 [32][1024]
constexpr size_t OFF_POOL = OFF_PART + 32ull*1024*4;            // f32 [B][D]
constexpr size_t OFF_CMT  = OFF_POOL + 2048ull*4;               // f32 [B]

// ---------- transpose f32 [R][C] -> bf16 [Npad][Rpad]
__global__ __launch_bounds__(256)
void transpose_w(const float* __restrict__ src, bfbits* __restrict__ dst,
                 int R, int C, int Rpad, int Npad) {
  __shared__ float tile[32][33];
  const int kb = blockIdx.x * 32, nb = blockIdx.y * 32;
  const int tx = threadIdx.x & 31, ty = threadIdx.x >> 5;
  for (int i = ty; i < 32; i += 8) {
    const int k = kb + i, n = nb + tx;
    tile[i][tx] = (k < R && n < C) ? src[(size_t)k * C + n] : 0.f;
  }
  __syncthreads();
  for (int i = ty; i < 32; i += 8) {
    const int n = nb + i, k = kb + tx;
    if (n < Npad && k < Rpad) dst[(size_t)n * Rpad + k] = f2bf(tile[tx][i]);
  }
}

// ---------- GEMV: out[b][d] = f(vec[b] @ w[.][d] + bias[d])
__global__ __launch_bounds__(256)
void gemv_t(const float* __restrict__ v, const float* __restrict__ w,
            const float* __restrict__ bias, float* __restrict__ out,
            int tanh_mode) {
  const int b = blockIdx.y;
  const int dl = threadIdx.x & 31, cl = threadIdx.x >> 5;
  const int d = blockIdx.x * 32 + dl;
  const float* vb = v + b * 1024;
  float s = 0.f;
  #pragma unroll 4
  for (int c = cl; c < 1024; c += 8)
    s += vb[c] * w[(size_t)c * 1024 + d];
  __shared__ float red[8][32];
  red[cl][dl] = s;
  __syncthreads();
  if (threadIdx.x < 32) {
    float t = 0.f;
    #pragma unroll
    for (int i = 0; i < 8; ++i) t += red[i][threadIdx.x];
    const int dd = blockIdx.x * 32 + threadIdx.x;
    t += bias[dd];
    out[b * 1024 + dd] = tanh_mode ? tanhf(t) : t;
  }
}

__global__ __launch_bounds__(256)
void cb_kernel(const float* __restrict__ cfa, const float* __restrict__ cbw,
               float* __restrict__ cbv) {
  const int b = blockIdx.x, tid = threadIdx.x;
  float4 a = *(const float4*)(cfa + b * 1024 + tid * 4);
  float4 w = *(const float4*)(cbw + tid * 4);
  float s = a.x * w.x + a.y * w.y + a.z * w.z + a.w * w.w;
  #pragma unroll
  for (int o = 32; o > 0; o >>= 1) s += __shfl_xor(s, o);
  __shared__ float ls[4];
  if ((tid & 63) == 0) ls[tid >> 6] = s;
  __syncthreads();
  if (tid == 0) cbv[b] = ls[0] + ls[1] + ls[2] + ls[3];
}

__device__ __forceinline__ void blockreduce3(float& a, float& b, float& c) {
  #pragma unroll
  for (int o = 32; o > 0; o >>= 1) {
    a += __shfl_xor(a, o);
    b += __shfl_xor(b, o);
    c += __shfl_xor(c, o);
  }
  __shared__ float ls[3][4];
  const int lane = threadIdx.x & 63, w = threadIdx.x >> 6;
  if (lane == 0) { ls[0][w] = a; ls[1][w] = b; ls[2][w] = c; }
  __syncthreads();
  a = ls[0][0] + ls[0][1] + ls[0][2] + ls[0][3];
  b = ls[1][0] + ls[1][1] + ls[1][2] + ls[1][3];
  c = ls[2][0] + ls[2][1] + ls[2][2] + ls[2][3];
}

// ---------- fused: x1 = x + bvec ; gate ; LN(x1) -> h (bf16)
__global__ __launch_bounds__(256)
void ln1_kernel(const float* __restrict__ x, const float* __restrict__ bvec,
                const float* __restrict__ cbv, const float* __restrict__ gw,
                const float* __restrict__ gb, const float* __restrict__ nfg,
                const float* __restrict__ nfb, float* __restrict__ x1,
                bfbits* __restrict__ h, float* __restrict__ gate_ws,
                float* __restrict__ gate_out) {
  const int m = blockIdx.x, tid = threadIdx.x, b = m >> 11;
  const size_t ro = (size_t)m * D_ + tid * 4;
  float4 xv = *(const float4*)(x + ro);
  float4 bv = *(const float4*)(bvec + b * D_ + tid * 4);
  float4 v;
  v.x = xv.x + bv.x; v.y = xv.y + bv.y; v.z = xv.z + bv.z; v.w = xv.w + bv.w;
  float4 g4 = *(const float4*)(gw + tid * 4);
  float s  = v.x + v.y + v.z + v.w;
  float s2 = v.x*v.x + v.y*v.y + v.z*v.z + v.w*v.w;
  float dg = v.x*g4.x + v.y*g4.y + v.z*g4.z + v.w*g4.w;
  blockreduce3(s, s2, dg);
  const float mean = s * (1.0f/1024.0f);
  const float var  = s2 * (1.0f/1024.0f) - mean*mean;
  const float rstd = rsqrtf(var + 1e-5f);
  if (tid == 0) {
    const float logits = dg + gb[0] + cbv[b];
    const float prob = 1.0f / (1.0f + expf(-logits));
    const float hard = prob > 0.5f ? 1.0f : 0.0f;
    const float gv = (hard - prob) + prob;
    gate_ws[m] = gv; gate_out[m] = gv;
  }
  *(float4*)(x1 + ro) = v;
  float4 gg = *(const float4*)(nfg + tid * 4);
  float4 b2 = *(const float4*)(nfb + tid * 4);
  u16x4 hv;
  hv[0] = f2bf((v.x - mean) * rstd * gg.x + b2.x);
  hv[1] = f2bf((v.y - mean) * rstd * gg.y + b2.y);
  hv[2] = f2bf((v.z - mean) * rstd * gg.z + b2.z);
  hv[3] = f2bf((v.w - mean) * rstd * gg.w + b2.w);
  *(u16x4*)(h + ro) = hv;
}

__global__ __launch_bounds__(256)
void ln2_kernel(const float* __restrict__ x2, const float* __restrict__ gptr,
                const float* __restrict__ bptr, bfbits* __restrict__ h2) {
  const int m = blockIdx.x, tid = threadIdx.x;
  const size_t ro = (size_t)m * D_ + tid * 4;
  float4 v = *(const float4*)(x2 + ro);
  float s  = v.x + v.y + v.z + v.w;
  float s2 = v.x*v.x + v.y*v.y + v.z*v.z + v.w*v.w;
  float d0 = 0.f;
  blockreduce3(s, s2, d0);
  const float mean = s * (1.0f/1024.0f);
  const float var  = s2 * (1.0f/1024.0f) - mean*mean;
  const float rstd = rsqrtf(var + 1e-5f);
  float4 gg = *(const float4*)(gptr + tid * 4);
  float4 b2 = *(const float4*)(bptr + tid * 4);
  u16x4 hv;
  hv[0] = f2bf((v.x - mean) * rstd * gg.x + b2.x);
  hv[1] = f2bf((v.y - mean) * rstd * gg.y + b2.y);
  hv[2] = f2bf((v.z - mean) * rstd * gg.z + b2.z);
  hv[3] = f2bf((v.w - mean) * rstd * gg.w + b2.w);
  *(u16x4*)(h2 + ro) = hv;
}

// ---------- GEMM: C[M][N] = A[M][K](bf16) * Bt[N][K](bf16), double-buffered LDS,
// XOR-swizzled staging (source-side) so ds_read_b128 is ~conflict-free.
// EPI 0: QKV (rope+gate, Q*(1/8)*log2e; V -> V^T)  [BM=128]
// EPI 1: WO (x2 = x1 + C*gate)                      [BM=64]
// EPI 2: UP (gelu(C+up_b) -> bf16, ldc=1664)        [BM=64]
// EPI 3: DN fused final (outx = x2+cmt*gate*(C+b))  [BM=64]
template <int EPI, int BM>
__global__ void __launch_bounds__(256, 2)
gemm_bt(const bfbits* __restrict__ A, int lda,
        const bfbits* __restrict__ Bt, int ldb, int K,
        const float* __restrict__ p0, const float* __restrict__ p1,
        const float* __restrict__ p2,
        float* __restrict__ fo0, const float* __restrict__ fo1,
        bfbits* __restrict__ bo0, bfbits* __restrict__ bo1,
        bfbits* __restrict__ bo2) {
  constexpr int MI = BM / 32;               // m-fragments per wave
  __shared__ bfbits Asl[2][BM * 32];
  __shared__ bfbits Bsl[2][128 * 32];
  const int tid = threadIdx.x;
  const int lane = tid & 63, wave = tid >> 6;
  const int g = lane >> 4, l15 = lane & 15;
  const int wr = wave >> 1, wc = wave & 1;
  const int m0 = blockIdx.y * BM, n0 = blockIdx.x * 128;

  // stage k-slab k0 into buffer p; source element offset XOR-swizzled so the
  // (linear-dest) global_load_lds yields a bank-friendly layout.
  auto stage = [&](int k0, int p) {
    #pragma unroll
    for (int i = 0; i < BM / 64; ++i) {
      const int c = i * 256 + tid;          // 16B chunk id, row = c>>2
      const int row = c >> 2;
      const int sw = (row & 3) ^ ((row >> 2) & 3);
      const int ko = ((c & 3) ^ sw) * 8;
      gload16(A + (size_t)(m0 + row) * lda + (k0 + ko),
              (char*)&Asl[p][0] + c * 16);
    }
    #pragma unroll
    for (int i = 0; i < 2; ++i) {
      const int c = i * 256 + tid;
      const int row = c >> 2;
      const int sw = (row & 3) ^ ((row >> 2) & 3);
      const int ko = ((c & 3) ^ sw) * 8;
      gload16(Bt + (size_t)(n0 + row) * ldb + (k0 + ko),
              (char*)&Bsl[p][0] + c * 16);
    }
  };

  f32x4 acc[MI][4] = {};
  stage(0, 0);
  __syncthreads();

  int t = 0;
  for (int k0 = 0; k0 < K; k0 += 32, ++t) {
    const int p = t & 1;
    if (k0 + 32 < K) stage(k0 + 32, p ^ 1);
    s16x8 af[MI], bfr[4];
    #pragma unroll
    for (int i = 0; i < MI; ++i) {
      const int row = wr * (MI * 16) + i * 16 + l15;
      const int sw = (row & 3) ^ ((row >> 2) & 3);
      af[i] = *(const s16x8*)&Asl[p][row * 32 + (g ^ sw) * 8];
    }
    #pragma unroll
    for (int i = 0; i < 4; ++i) {
      const int row = wc * 64 + i * 16 + l15;
      const int sw = (row & 3) ^ ((row >> 2) & 3);
      bfr[i] = *(const s16x8*)&Bsl[p][row * 32 + (g ^ sw) * 8];
    }
    #pragma unroll
    for (int i = 0; i < MI; ++i)
      #pragma unroll
      for (int j = 0; j < 4; ++j)
        acc[i][j] = __builtin_amdgcn_mfma_f32_16x16x32_bf16(af[i], bfr[j], acc[i][j], 0, 0, 0);
    __syncthreads();
  }

  const int b = m0 >> 11;
  const int trow0 = (m0 & 2047) + wr * (MI * 16);

  if constexpr (EPI == 0) {
    const float* gate = p0;
    const float* phase = p1;
    const int ncol0 = n0 + wc * 64;
    const int section = ncol0 >> 10;          // 0=Q 1=K 2=V
    const int hh = (ncol0 & 1023) >> 6;
    if (section == 2) {
      bfbits* vt = bo2;
      const size_t vhead = (size_t)(b * H_ + hh) * DH_ * T_;
      #pragma unroll
      for (int mi = 0; mi < MI; ++mi) {
        const int tb = trow0 + mi * 16 + g * 4;
        #pragma unroll
        for (int ni = 0; ni < 4; ++ni) {
          const int dh = ni * 16 + l15;
          unsigned* dst32 = (unsigned*)&vt[vhead + (size_t)dh * T_ + tb];
          dst32[0] = pkbf(acc[mi][ni][0], acc[mi][ni][1]);
          dst32[1] = pkbf(acc[mi][ni][2], acc[mi][ni][3]);
        }
      }
    } else {
      const float cc = cosf(phase[hh]);
      const float ssn = sinf(phase[hh]);
      // Q carries 1/sqrt(DH) and log2(e): scores land in exp2 domain.
      const float qs = (section == 0) ? 0.125f * 1.44269504088896341f : 1.0f;
      bfbits* dst = (section == 0) ? bo0 : bo1;
      const size_t head = (size_t)(b * H_ + hh) * T_ * DH_;
      #pragma unroll
      for (int mi = 0; mi < MI; ++mi) {
        const int tb = trow0 + mi * 16 + g * 4;
        float gv[4];
        #pragma unroll
        for (int r = 0; r < 4; ++r) gv[r] = gate[(size_t)b * T_ + tb + r] * qs;
        #pragma unroll
        for (int ni = 0; ni < 2; ++ni) {
          const int dh = ni * 16 + l15;
          #pragma unroll
          for (int r = 0; r < 4; ++r) {
            const float re = acc[mi][ni][r];
            const float im = acc[mi][ni + 2][r];
            const size_t idx = head + (size_t)(tb + r) * DH_ + dh;
            dst[idx]      = f2bf((re * cc - im * ssn) * gv[r]);
            dst[idx + 32] = f2bf((re * ssn + im * cc) * gv[r]);
          }
        }
      }
    }
  } else if constexpr (EPI == 1) {
    const float* gate = p0;
    const float* x1 = fo1;
    float* x2 = fo0;
    #pragma unroll
    for (int mi = 0; mi < MI; ++mi) {
      const int m = m0 + wr * (MI * 16) + mi * 16 + g * 4;
      float gv[4];
      #pragma unroll
      for (int r = 0; r < 4; ++r) gv[r] = gate[m + r];
      #pragma unroll
      for (int ni = 0; ni < 4; ++ni) {
        const int n = n0 + wc * 64 + ni * 16 + l15;
        #pragma unroll
        for (int r = 0; r < 4; ++r) {
          const size_t idx = (size_t)(m + r) * D_ + n;
          x2[idx] = x1[idx] + acc[mi][ni][r] * gv[r];
        }
      }
    }
  } else if constexpr (EPI == 2) {
    const float* upb = p0;
    bfbits* outm = bo0;
    #pragma unroll
    for (int mi = 0; mi < MI; ++mi) {
      const int m = m0 + wr * (MI * 16) + mi * 16 + g * 4;
      #pragma unroll
      for (int ni = 0; ni < 4; ++ni) {
        const int n = n0 + wc * 64 + ni * 16 + l15;
        const float bb = upb[n < DFF_ ? n : DFF_ - 1];
        #pragma unroll
        for (int r = 0; r < 4; ++r) {
          float v = acc[mi][ni][r] + bb;
          v = 0.5f * v * (1.0f + erff(v * 0.70710678118654752f));
          outm[(size_t)(m + r) * DFFP_ + n] = f2bf(v);
        }
      }
    }
  } else {
    const float* dnb = p0;
    const float* gate = p1;
    const float* cmt = p2;
    const float* x2 = fo1;
    float* outx = fo0;
    const float cb = cmt[b];
    #pragma unroll
    for (int mi = 0; mi < MI; ++mi) {
      const int m = m0 + wr * (MI * 16) + mi * 16 + g * 4;
      float kv[4];
      #pragma unroll
      for (int r = 0; r < 4; ++r) kv[r] = cb * gate[m + r];
      #pragma unroll
      for (int ni = 0; ni < 4; ++ni) {
        const int n = n0 + wc * 64 + ni * 16 + l15;
        const float bb = dnb[n];
        #pragma unroll
        for (int r = 0; r < 4; ++r) {
          const size_t idx = (size_t)(m + r) * D_ + n;
          outx[idx] = x2[idx] + kv[r] * (acc[mi][ni][r] + bb);
        }
      }
    }
  }
}

// ---------- flash attention v5: 2048 blocks x 2 waves, 16 q-rows/wave,
// KVBLK=32, 16KB LDS dbuf -> 8 blocks/CU co-resident (4 waves/SIMD).
// Heavy-first qt order; bh = pid&31 keeps per-XCD K/V set L2-resident.
__global__ void __launch_bounds__(128, 4)
attn_kernel(const bfbits* __restrict__ Qb, const bfbits* __restrict__ Kb,
            const bfbits* __restrict__ Vt, bfbits* __restrict__ AO) {
  __shared__ bfbits Kl[2][32 * 64];
  __shared__ bfbits Vl[2][64 * 32];
  const int pid = blockIdx.x;               // 0..2047
  const int bh = pid & 31;
  const int qt = 63 - (pid >> 5);           // heavy blocks first
  const int qb0 = qt * 32;
  const int tid = threadIdx.x, lane = tid & 63, wq = tid >> 6;
  const int g = lane >> 4, l15 = lane & 15;
  const int qrow_base = qb0 + wq * 16;

  const bfbits* Qp = Qb + ((size_t)bh * T_ + qrow_base) * DH_;
  const bfbits* Kp = Kb + (size_t)bh * T_ * DH_;
  const bfbits* Vp = Vt + (size_t)bh * DH_ * T_;

  const s16x8 qf0 = *(const s16x8*)(Qp + l15 * DH_ + g * 8);
  const s16x8 qf1 = *(const s16x8*)(Qp + l15 * DH_ + 32 + g * 8);

  f32x4 o[4] = {};
  float mrun = -INFINITY, lrun = 0.f;

  const int nk = qt + 1;                    // 32-wide k-tiles

  // per-thread staging addresses (loop-invariant parts hoisted)
  const int ck0 = tid,        ck1 = 128 + tid;        // K chunks
  const int kr0 = ck0 >> 3,   kr1 = ck1 >> 3;
  const int ks0 = (((ck0 & 7) ^ (kr0 & 7))) * 8;
  const int ks1 = (((ck1 & 7) ^ (kr1 & 7))) * 8;
  const bfbits* kg0 = Kp + kr0 * DH_ + ks0;
  const bfbits* kg1 = Kp + kr1 * DH_ + ks1;
  const int cv0 = tid,        cv1 = 128 + tid;        // V chunks
  const int vr0 = cv0 >> 2,   vr1 = cv1 >> 2;
  const int vs0 = (((cv0 & 3) ^ (vr0 & 3) ^ ((vr0 >> 2) & 3))) * 8;
  const int vs1 = (((cv1 & 3) ^ (vr1 & 3) ^ ((vr1 >> 2) & 3))) * 8;
  const bfbits* vg0 = Vp + (size_t)vr0 * T_ + vs0;
  const bfbits* vg1 = Vp + (size_t)vr1 * T_ + vs1;

  auto stage = [&](int k0, int p) {
    gload16(kg0 + (size_t)k0 * DH_, (char*)&Kl[p][0] + ck0 * 16);
    gload16(kg1 + (size_t)k0 * DH_, (char*)&Kl[p][0] + ck1 * 16);
    gload16(vg0 + k0, (char*)&Vl[p][0] + cv0 * 16);
    gload16(vg1 + k0, (char*)&Vl[p][0] + cv1 * 16);
  };

  stage(0, 0);
  __syncthreads();

  for (int t = 0; t < nk; ++t) {
    const int p = t & 1;
    if (t + 1 < nk) stage((t + 1) << 5, p ^ 1);
    const int k0 = t << 5;
    // ---- QK^T: S^T tile [32 k][16 q] ----
    f32x4 st[2];
    __builtin_amdgcn_s_setprio(1);
    #pragma unroll
    for (int kt = 0; kt < 2; ++kt) {
      const int krow = kt * 16 + l15;
      const int rs = krow & 7;
      const s16x8 ka  = *(const s16x8*)&Kl[p][krow * 64 + ((0 + g) ^ rs) * 8];
      const s16x8 kb2 = *(const s16x8*)&Kl[p][krow * 64 + ((4 + g) ^ rs) * 8];
      f32x4 z = {0.f, 0.f, 0.f, 0.f};
      z = __builtin_amdgcn_mfma_f32_16x16x32_bf16(ka,  qf0, z, 0, 0, 0);
      z = __builtin_amdgcn_mfma_f32_16x16x32_bf16(kb2, qf1, z, 0, 0, 0);
      st[kt] = z;
    }
    __builtin_amdgcn_s_setprio(0);
    // ---- online softmax (exp2 domain; lane-local in k; q = l15) ----
    const int qrow = qrow_base + l15;
    if (k0 + 31 > qrow_base) {              // diagonal tile (wave-uniform test)
      #pragma unroll
      for (int kt = 0; kt < 2; ++kt)
        #pragma unroll
        for (int r = 0; r < 4; ++r)
          if (k0 + kt * 16 + g * 4 + r > qrow) st[kt][r] = -1e9f;
    }
    float mx = fmaxf(fmaxf(fmaxf(st[0][0], st[0][1]), fmaxf(st[0][2], st[0][3])),
                     fmaxf(fmaxf(st[1][0], st[1][1]), fmaxf(st[1][2], st[1][3])));
    mx = fmaxf(mx, __shfl_xor(mx, 16));
    mx = fmaxf(mx, __shfl_xor(mx, 32));
    const bool need = __any(mx > mrun + 8.f) != 0;   // defer-max
    const float mnew = need ? fmaxf(mrun, mx) : mrun;
    float sum = 0.f;
    #pragma unroll
    for (int kt = 0; kt < 2; ++kt)
      #pragma unroll
      for (int r = 0; r < 4; ++r) {
        const float e = vexp2(st[kt][r] - mnew);
        st[kt][r] = e;
        sum += e;
      }
    sum += __shfl_xor(sum, 16);
    sum += __shfl_xor(sum, 32);
    if (need) {
      const float alpha = vexp2(mrun - mnew);
      mrun = mnew;
      lrun = lrun * alpha + sum;
      #pragma unroll
      for (int dt = 0; dt < 4; ++dt) {
        o[dt][0] *= alpha; o[dt][1] *= alpha;
        o[dt][2] *= alpha; o[dt][3] *= alpha;
      }
    } else {
      lrun += sum;
    }
    uint4 w;
    w.x = pkbf(st[0][0], st[0][1]);
    w.y = pkbf(st[0][2], st[0][3]);
    w.z = pkbf(st[1][0], st[1][1]);
    w.w = pkbf(st[1][2], st[1][3]);
    const s16x8 pf = __builtin_bit_cast(s16x8, w);
    // ---- PV: O^T += V^T * P^T (k-bijection j = kt*4+r matches pf) ----
    __builtin_amdgcn_s_setprio(1);
    #pragma unroll
    for (int dt = 0; dt < 4; ++dt) {
      const int vrow = dt * 16 + l15;
      const int sw = (vrow & 3) ^ ((vrow >> 2) & 3);
      const u16x4 vlo = *(const u16x4*)&Vl[p][vrow * 32 + (((g >> 1) ^ sw) * 8) + (g & 1) * 4];
      const u16x4 vhi = *(const u16x4*)&Vl[p][vrow * 32 + ((((g >> 1) + 2) ^ sw) * 8) + (g & 1) * 4];
      s16x8 vf;
      vf[0] = (short)vlo[0]; vf[1] = (short)vlo[1]; vf[2] = (short)vlo[2]; vf[3] = (short)vlo[3];
      vf[4] = (short)vhi[0]; vf[5] = (short)vhi[1]; vf[6] = (short)vhi[2]; vf[7] = (short)vhi[3];
      o[dt] = __builtin_amdgcn_mfma_f32_16x16x32_bf16(vf, pf, o[dt], 0, 0, 0);
    }
    __builtin_amdgcn_s_setprio(0);
    __syncthreads();
  }

  const float inv = 1.0f / lrun;
  const int b = bh >> 4, hh = bh & 15;
  bfbits* dst = AO + ((size_t)b * T_ + qrow_base + l15) * D_ + hh * DH_;
  #pragma unroll
  for (int dt = 0; dt < 4; ++dt) {
    unsigned* d32 = (unsigned*)&dst[dt * 16 + g * 4];
    d32[0] = pkbf(o[dt][0] * inv, o[dt][1] * inv);
    d32[1] = pkbf(o[dt][2] * inv, o[dt][3] * inv);
  }
}

// ---------- pooling / commit ----------
__global__ __launch_bounds__(256)
void pool_part(const float* __restrict__ x2, float* __restrict__ part) {
  const int s = blockIdx.x, b = blockIdx.y, tid = threadIdx.x;
  const float* base = x2 + ((size_t)b * T_ + s * 128) * D_ + tid * 4;
  float ax = 0, ay = 0, az = 0, aw = 0;
  for (int t = 0; t < 128; ++t) {
    float4 v = *(const float4*)(base + (size_t)t * D_);
    ax += v.x; ay += v.y; az += v.z; aw += v.w;
  }
  float4 ov; ov.x = ax; ov.y = ay; ov.z = az; ov.w = aw;
  *(float4*)(part + (size_t)(b * 16 + s) * D_ + tid * 4) = ov;
}

__global__ __launch_bounds__(256)
void pool_fin(const float* __restrict__ part, float* __restrict__ pool) {
  const int idx = blockIdx.x * 256 + threadIdx.x; // 0..2047
  const int b = idx >> 10, d = idx & 1023;
  float s = 0.f;
  for (int i = 0; i < 16; ++i) s += part[(size_t)(b * 16 + i) * D_ + d];
  pool[idx] = s * (1.0f / 2048.0f);
}

__global__ __launch_bounds__(256)
void commit_kernel(const float* __restrict__ pool, const float* __restrict__ cw,
                   const float* __restrict__ cb0, float* __restrict__ cmt,
                   float* __restrict__ out_cmt) {
  const int b = blockIdx.x, tid = threadIdx.x;
  float4 p = *(const float4*)(pool + b * 1024 + tid * 4);
  float4 w = *(const float4*)(cw + tid * 4);
  float s = p.x * w.x + p.y * w.y + p.z * w.z + p.w * w.w;
  #pragma unroll
  for (int o = 32; o > 0; o >>= 1) s += __shfl_xor(s, o);
  __shared__ float ls[4];
  if ((tid & 63) == 0) ls[tid >> 6] = s;
  __syncthreads();
  if (tid == 0) {
    const float t = ls[0] + ls[1] + ls[2] + ls[3] + cb0[0];
    const float v = 1.0f / (1.0f + expf(-t));
    cmt[b] = v; out_cmt[b] = v;
  }
}

// ---------------- host launcher ----------------
extern "C" void kernel_launch(void* const* d_in, const int* in_sizes, int n_in,
                              void* d_out, int out_size, void* d_ws, size_t ws_size,
                              hipStream_t stream) {
  (void)in_sizes; (void)n_in; (void)out_size; (void)ws_size;
  const float* x       = (const float*)d_in[0];
  const float* cfa     = (const float*)d_in[1];
  const float* gate_w  = (const float*)d_in[3];
  const float* gate_b  = (const float*)d_in[4];
  const float* cb_w    = (const float*)d_in[5];
  const float* nf_g    = (const float*)d_in[6];
  const float* nf_b    = (const float*)d_in[7];
  const float* wq      = (const float*)d_in[8];
  const float* wk      = (const float*)d_in[9];
  const float* wv      = (const float*)d_in[10];
  const float* wo      = (const float*)d_in[11];
  const float* phase   = (const float*)d_in[12];
  const float* nb_g    = (const float*)d_in[13];
  const float* nb_b    = (const float*)d_in[14];
  const float* up_w    = (const float*)d_in[15];
  const float* up_b    = (const float*)d_in[16];
  const float* dn_w    = (const float*)d_in[17];
  const float* dn_b    = (const float*)d_in[18];
  const float* cmt_w   = (const float*)d_in[19];
  const float* cmt_b   = (const float*)d_in[20];
  const float* cproj_w = (const float*)d_in[21];
  const float* cproj_b = (const float*)d_in[22];
  const float* bcast_w = (const float*)d_in[23];
  const float* bcast_b = (const float*)d_in[24];

  char* ws = (char*)d_ws;
  float*  x1     = (float*)(ws + OFF_X1);
  bfbits* h      = (bfbits*)(ws + OFF_H);
  bfbits* h2     = (bfbits*)(ws + OFF_H);     // alias: h dead after QKV
  bfbits* qb     = (bfbits*)(ws + OFF_Q);
  bfbits* kb     = (bfbits*)(ws + OFF_K);
  bfbits* vt     = (bfbits*)(ws + OFF_VT);
  bfbits* ffmid  = (bfbits*)(ws + OFF_Q);     // alias: Q/K dead after attention
  bfbits* ao     = (bfbits*)(ws + OFF_AO);
  float*  x2     = (float*)(ws + OFF_X2);
  bfbits* wqkv_t = (bfbits*)(ws + OFF_WQKV);
  bfbits* wo_t   = (bfbits*)(ws + OFF_WO);
  bfbits* wup_t  = (bfbits*)(ws + OFF_WUP);
  bfbits* wdn_t  = (bfbits*)(ws + OFF_WDN);
  float*  bvec   = (float*)(ws + OFF_BVEC);
  float*  cbv    = (float*)(ws + OFF_CBV);
  float*  gate   = (float*)(ws + OFF_GATE);
  float*  part   = (float*)(ws + OFF_PART);
  float*  pool   = (float*)(ws + OFF_POOL);
  float*  cmt    = (float*)(ws + OFF_CMT);

  float* outx   = (float*)d_out;
  float* outc   = outx + NELEM_X;          // center [B][DC]
  float* outg   = outc + B_ * DC_;         // gate [B][T]
  float* outcmt = outg + B_ * T_;          // commit [B]

  // weight prep (B^T bf16)
  transpose_w<<<dim3(32, 32), 256, 0, stream>>>(wq, wqkv_t,                1024, 1024, 1024, 1024);
  transpose_w<<<dim3(32, 32), 256, 0, stream>>>(wk, wqkv_t + 1024 * 1024,  1024, 1024, 1024, 1024);
  transpose_w<<<dim3(32, 32), 256, 0, stream>>>(wv, wqkv_t + 2048 * 1024,  1024, 1024, 1024, 1024);
  transpose_w<<<dim3(32, 32), 256, 0, stream>>>(wo, wo_t,                  1024, 1024, 1024, 1024);
  transpose_w<<<dim3(32, 52), 256, 0, stream>>>(up_w, wup_t,               1024, DFF_, 1024, DFFP_);
  transpose_w<<<dim3(52, 32), 256, 0, stream>>>(dn_w, wdn_t,               DFF_, 1024, DFFP_, 1024);

  gemv_t<<<dim3(32, B_), 256, 0, stream>>>(cfa, bcast_w, bcast_b, bvec, 0);
  cb_kernel<<<B_, 256, 0, stream>>>(cfa, cb_w, cbv);

  ln1_kernel<<<MTOT, 256, 0, stream>>>(x, bvec, cbv, gate_w, gate_b, nf_g, nf_b,
                                       x1, h, gate, outg);

  gemm_bt<0, 128><<<dim3(24, 32), 256, 0, stream>>>(
      h, 1024, wqkv_t, 1024, 1024, gate, phase, nullptr,
      nullptr, nullptr, qb, kb, vt);

  attn_kernel<<<2048, 128, 0, stream>>>(qb, kb, vt, ao);

  gemm_bt<1, 64><<<dim3(8, 64), 256, 0, stream>>>(
      ao, 1024, wo_t, 1024, 1024, gate, nullptr, nullptr,
      x2, x1, nullptr, nullptr, nullptr);

  ln2_kernel<<<MTOT, 256, 0, stream>>>(x2, nb_g, nb_b, h2);

  // pooled stats only need x2 -> run before FF so DN can fuse the final add
  pool_part<<<dim3(16, B_), 256, 0, stream>>>(x2, part);
  pool_fin<<<8, 256, 0, stream>>>(part, pool);
  commit_kernel<<<B_, 256, 0, stream>>>(pool, cmt_w, cmt_b, cmt, outcmt);
  gemv_t<<<dim3(32, B_), 256, 0, stream>>>(pool, cproj_w, cproj_b, outc, 1);

  gemm_bt<2, 64><<<dim3(13, 64), 256, 0, stream>>>(
      h2, 1024, wup_t, 1024, 1024, up_b, nullptr, nullptr,
      nullptr, nullptr, ffmid, nullptr, nullptr);

  gemm_bt<3, 64><<<dim3(8, 64), 256, 0, stream>>>(
      ffmid, DFFP_, wdn_t, DFFP_, DFFP_, dn_b, gate, cmt,
      outx, x2, nullptr, nullptr, nullptr);
}

// Round 7
// 258.252 us; speedup vs baseline: 1.0548x; 1.0548x over previous
//
#include <hip/hip_runtime.h>
#include <math.h>

// ---- problem constants ----
#define B_   2
#define T_   2048
#define D_   1024
#define H_   16
#define DH_  64
#define DC_  1024
#define DFF_ 1656
#define DFFP_ 1664
#define MTOT 4096          // B_*T_
#define NELEM_X 4194304ull // B*T*D

typedef short s16x8 __attribute__((ext_vector_type(8)));
typedef unsigned short u16x4 __attribute__((ext_vector_type(4)));
typedef float f32x4 __attribute__((ext_vector_type(4)));
typedef float f32x16 __attribute__((ext_vector_type(16)));
typedef unsigned short bfbits;

__device__ __forceinline__ bfbits f2bf(float f) {
  unsigned int u = __builtin_bit_cast(unsigned int, f);
  u += 0x7fffu + ((u >> 16) & 1u);          // RNE
  return (bfbits)(u >> 16);
}

__device__ __forceinline__ float vexp2(float x) {   // 2^x via HW transcendental
  float r;
  asm("v_exp_f32 %0, %1" : "=v"(r) : "v"(x));
  return r;
}
__device__ __forceinline__ unsigned pkbf(float lo, float hi) { // 2xbf16 pack, RNE
  unsigned r;
  asm("v_cvt_pk_bf16_f32 %0, %1, %2" : "=v"(r) : "v"(lo), "v"(hi));
  return r;
}

__device__ __forceinline__ void gload16(const void* g, void* l) {
  __builtin_amdgcn_global_load_lds(
      (__attribute__((address_space(1))) void*)g,
      (__attribute__((address_space(3))) void*)l, 16, 0, 0);
}

// ---------- workspace offsets (bytes) ----------
constexpr size_t OFF_X1   = 0;                                  // f32 x1
constexpr size_t OFF_H    = OFF_X1 + 4ull*NELEM_X;              // bf16 h ; later h2
constexpr size_t OFF_Q    = OFF_H  + 2ull*NELEM_X;              // bf16 Q [BH][T][64] ; later ffmid
constexpr size_t OFF_K    = OFF_Q  + 2ull*NELEM_X;              // bf16 K [BH][T][64]
constexpr size_t OFF_VT   = OFF_K  + 2ull*NELEM_X;              // bf16 V^T [BH][64][T]
constexpr size_t OFF_AO   = OFF_VT + 2ull*NELEM_X;              // bf16 attn out [M][D]
constexpr size_t OFF_X2   = OFF_AO + 2ull*NELEM_X;              // f32 x2
constexpr size_t OFF_WQKV = OFF_X2 + 4ull*NELEM_X;              // bf16 [3072][1024]
constexpr size_t OFF_WO   = OFF_WQKV + 3072ull*1024*2;          // bf16 [1024][1024]
constexpr size_t OFF_WUP  = OFF_WO   + 1024ull*1024*2;          // bf16 [1664][1024]
constexpr size_t OFF_WDN  = OFF_WUP  + 1664ull*1024*2;          // bf16 [1024][1664]
constexpr size_t OFF_BVEC = OFF_WDN  + 1024ull*1664*2;          // f32 [B][D]
constexpr size_t OFF_CBV  = OFF_BVEC + 2048ull*4;               // f32 [B]
constexpr size_t OFF_GATE = OFF_CBV  + 256;                     // f32 [M]
constexpr size_t OFF_PART = OFF_GATE + 4096ull*4;               // f32 [128][1024]
constexpr size_t OFF_POOL = OFF_PART + 128ull*1024*4;           // f32 [B][D]
constexpr size_t OFF_CMT  = OFF_POOL + 2048ull*4;               // f32 [B]

// ---------- transpose f32 [R][C] -> bf16 [Npad][Rpad]
__global__ __launch_bounds__(256)
void transpose_w(const float* __restrict__ src, bfbits* __restrict__ dst,
                 int R, int C, int Rpad, int Npad) {
  __shared__ float tile[32][33];
  const int kb = blockIdx.x * 32, nb = blockIdx.y * 32;
  const int tx = threadIdx.x & 31, ty = threadIdx.x >> 5;
  for (int i = ty; i < 32; i += 8) {
    const int k = kb + i, n = nb + tx;
    tile[i][tx] = (k < R && n < C) ? src[(size_t)k * C + n] : 0.f;
  }
  __syncthreads();
  for (int i = ty; i < 32; i += 8) {
    const int n = nb + i, k = kb + tx;
    if (n < Npad && k < Rpad) dst[(size_t)n * Rpad + k] = f2bf(tile[tx][i]);
  }
}

// ---------- GEMV: out[b][d] = f(vec[b] @ w[.][d] + bias[d])
__global__ __launch_bounds__(256)
void gemv_t(const float* __restrict__ v, const float* __restrict__ w,
            const float* __restrict__ bias, float* __restrict__ out,
            int tanh_mode) {
  const int b = blockIdx.y;
  const int dl = threadIdx.x & 31, cl = threadIdx.x >> 5;
  const int d = blockIdx.x * 32 + dl;
  const float* vb = v + b * 1024;
  float s = 0.f;
  #pragma unroll 4
  for (int c = cl; c < 1024; c += 8)
    s += vb[c] * w[(size_t)c * 1024 + d];
  __shared__ float red[8][32];
  red[cl][dl] = s;
  __syncthreads();
  if (threadIdx.x < 32) {
    float t = 0.f;
    #pragma unroll
    for (int i = 0; i < 8; ++i) t += red[i][threadIdx.x];
    const int dd = blockIdx.x * 32 + threadIdx.x;
    t += bias[dd];
    out[b * 1024 + dd] = tanh_mode ? tanhf(t) : t;
  }
}

__global__ __launch_bounds__(256)
void cb_kernel(const float* __restrict__ cfa, const float* __restrict__ cbw,
               float* __restrict__ cbv) {
  const int b = blockIdx.x, tid = threadIdx.x;
  float4 a = *(const float4*)(cfa + b * 1024 + tid * 4);
  float4 w = *(const float4*)(cbw + tid * 4);
  float s = a.x * w.x + a.y * w.y + a.z * w.z + a.w * w.w;
  #pragma unroll
  for (int o = 32; o > 0; o >>= 1) s += __shfl_xor(s, o);
  __shared__ float ls[4];
  if ((tid & 63) == 0) ls[tid >> 6] = s;
  __syncthreads();
  if (tid == 0) cbv[b] = ls[0] + ls[1] + ls[2] + ls[3];
}

__device__ __forceinline__ void blockreduce3(float& a, float& b, float& c) {
  #pragma unroll
  for (int o = 32; o > 0; o >>= 1) {
    a += __shfl_xor(a, o);
    b += __shfl_xor(b, o);
    c += __shfl_xor(c, o);
  }
  __shared__ float ls[3][4];
  const int lane = threadIdx.x & 63, w = threadIdx.x >> 6;
  if (lane == 0) { ls[0][w] = a; ls[1][w] = b; ls[2][w] = c; }
  __syncthreads();
  a = ls[0][0] + ls[0][1] + ls[0][2] + ls[0][3];
  b = ls[1][0] + ls[1][1] + ls[1][2] + ls[1][3];
  c = ls[2][0] + ls[2][1] + ls[2][2] + ls[2][3];
}

// ---------- fused: x1 = x + bvec ; gate ; LN(x1) -> h (bf16)
__global__ __launch_bounds__(256)
void ln1_kernel(const float* __restrict__ x, const float* __restrict__ bvec,
                const float* __restrict__ cbv, const float* __restrict__ gw,
                const float* __restrict__ gb, const float* __restrict__ nfg,
                const float* __restrict__ nfb, float* __restrict__ x1,
                bfbits* __restrict__ h, float* __restrict__ gate_ws,
                float* __restrict__ gate_out) {
  const int m = blockIdx.x, tid = threadIdx.x, b = m >> 11;
  const size_t ro = (size_t)m * D_ + tid * 4;
  float4 xv = *(const float4*)(x + ro);
  float4 bv = *(const float4*)(bvec + b * D_ + tid * 4);
  float4 v;
  v.x = xv.x + bv.x; v.y = xv.y + bv.y; v.z = xv.z + bv.z; v.w = xv.w + bv.w;
  float4 g4 = *(const float4*)(gw + tid * 4);
  float s  = v.x + v.y + v.z + v.w;
  float s2 = v.x*v.x + v.y*v.y + v.z*v.z + v.w*v.w;
  float dg = v.x*g4.x + v.y*g4.y + v.z*g4.z + v.w*g4.w;
  blockreduce3(s, s2, dg);
  const float mean = s * (1.0f/1024.0f);
  const float var  = s2 * (1.0f/1024.0f) - mean*mean;
  const float rstd = rsqrtf(var + 1e-5f);
  if (tid == 0) {
    const float logits = dg + gb[0] + cbv[b];
    const float prob = 1.0f / (1.0f + expf(-logits));
    const float hard = prob > 0.5f ? 1.0f : 0.0f;
    const float gv = (hard - prob) + prob;
    gate_ws[m] = gv; gate_out[m] = gv;
  }
  *(float4*)(x1 + ro) = v;
  float4 gg = *(const float4*)(nfg + tid * 4);
  float4 b2 = *(const float4*)(nfb + tid * 4);
  u16x4 hv;
  hv[0] = f2bf((v.x - mean) * rstd * gg.x + b2.x);
  hv[1] = f2bf((v.y - mean) * rstd * gg.y + b2.y);
  hv[2] = f2bf((v.z - mean) * rstd * gg.z + b2.z);
  hv[3] = f2bf((v.w - mean) * rstd * gg.w + b2.w);
  *(u16x4*)(h + ro) = hv;
}

__global__ __launch_bounds__(256)
void ln2_kernel(const float* __restrict__ x2, const float* __restrict__ gptr,
                const float* __restrict__ bptr, bfbits* __restrict__ h2) {
  const int m = blockIdx.x, tid = threadIdx.x;
  const size_t ro = (size_t)m * D_ + tid * 4;
  float4 v = *(const float4*)(x2 + ro);
  float s  = v.x + v.y + v.z + v.w;
  float s2 = v.x*v.x + v.y*v.y + v.z*v.z + v.w*v.w;
  float d0 = 0.f;
  blockreduce3(s, s2, d0);
  const float mean = s * (1.0f/1024.0f);
  const float var  = s2 * (1.0f/1024.0f) - mean*mean;
  const float rstd = rsqrtf(var + 1e-5f);
  float4 gg = *(const float4*)(gptr + tid * 4);
  float4 b2 = *(const float4*)(bptr + tid * 4);
  u16x4 hv;
  hv[0] = f2bf((v.x - mean) * rstd * gg.x + b2.x);
  hv[1] = f2bf((v.y - mean) * rstd * gg.y + b2.y);
  hv[2] = f2bf((v.z - mean) * rstd * gg.z + b2.z);
  hv[3] = f2bf((v.w - mean) * rstd * gg.w + b2.w);
  *(u16x4*)(h2 + ro) = hv;
}

// ---------- GEMM: C[M][N] = A[M][K](bf16) * Bt[N][K](bf16), double-buffered LDS,
// XOR-swizzled staging (source-side) so ds_read_b128 is ~conflict-free.
// EPI 0: QKV (rope+gate, Q*(1/8)*log2e; V -> V^T)  [BM=128]
// EPI 1: WO (x2 = x1 + C*gate)                      [BM=64]
// EPI 2: UP (gelu(C+up_b) -> bf16, ldc=1664)        [BM=64]
// EPI 3: DN fused final (outx = x2+cmt*gate*(C+b))  [BM=64]
template <int EPI, int BM>
__global__ void __launch_bounds__(256, 2)
gemm_bt(const bfbits* __restrict__ A, int lda,
        const bfbits* __restrict__ Bt, int ldb, int K,
        const float* __restrict__ p0, const float* __restrict__ p1,
        const float* __restrict__ p2,
        float* __restrict__ fo0, const float* __restrict__ fo1,
        bfbits* __restrict__ bo0, bfbits* __restrict__ bo1,
        bfbits* __restrict__ bo2) {
  constexpr int MI = BM / 32;               // m-fragments per wave
  __shared__ bfbits Asl[2][BM * 32];
  __shared__ bfbits Bsl[2][128 * 32];
  const int tid = threadIdx.x;
  const int lane = tid & 63, wave = tid >> 6;
  const int g = lane >> 4, l15 = lane & 15;
  const int wr = wave >> 1, wc = wave & 1;
  const int m0 = blockIdx.y * BM, n0 = blockIdx.x * 128;

  auto stage = [&](int k0, int p) {
    #pragma unroll
    for (int i = 0; i < BM / 64; ++i) {
      const int c = i * 256 + tid;          // 16B chunk id, row = c>>2
      const int row = c >> 2;
      const int sw = (row & 3) ^ ((row >> 2) & 3);
      const int ko = ((c & 3) ^ sw) * 8;
      gload16(A + (size_t)(m0 + row) * lda + (k0 + ko),
              (char*)&Asl[p][0] + c * 16);
    }
    #pragma unroll
    for (int i = 0; i < 2; ++i) {
      const int c = i * 256 + tid;
      const int row = c >> 2;
      const int sw = (row & 3) ^ ((row >> 2) & 3);
      const int ko = ((c & 3) ^ sw) * 8;
      gload16(Bt + (size_t)(n0 + row) * ldb + (k0 + ko),
              (char*)&Bsl[p][0] + c * 16);
    }
  };

  f32x4 acc[MI][4] = {};
  stage(0, 0);
  __syncthreads();

  int t = 0;
  for (int k0 = 0; k0 < K; k0 += 32, ++t) {
    const int p = t & 1;
    if (k0 + 32 < K) stage(k0 + 32, p ^ 1);
    s16x8 af[MI], bfr[4];
    #pragma unroll
    for (int i = 0; i < MI; ++i) {
      const int row = wr * (MI * 16) + i * 16 + l15;
      const int sw = (row & 3) ^ ((row >> 2) & 3);
      af[i] = *(const s16x8*)&Asl[p][row * 32 + (g ^ sw) * 8];
    }
    #pragma unroll
    for (int i = 0; i < 4; ++i) {
      const int row = wc * 64 + i * 16 + l15;
      const int sw = (row & 3) ^ ((row >> 2) & 3);
      bfr[i] = *(const s16x8*)&Bsl[p][row * 32 + (g ^ sw) * 8];
    }
    #pragma unroll
    for (int i = 0; i < MI; ++i)
      #pragma unroll
      for (int j = 0; j < 4; ++j)
        acc[i][j] = __builtin_amdgcn_mfma_f32_16x16x32_bf16(af[i], bfr[j], acc[i][j], 0, 0, 0);
    __syncthreads();
  }

  const int b = m0 >> 11;
  const int trow0 = (m0 & 2047) + wr * (MI * 16);

  if constexpr (EPI == 0) {
    const float* gate = p0;
    const float* phase = p1;
    const int ncol0 = n0 + wc * 64;
    const int section = ncol0 >> 10;          // 0=Q 1=K 2=V
    const int hh = (ncol0 & 1023) >> 6;
    if (section == 2) {
      bfbits* vt = bo2;
      const size_t vhead = (size_t)(b * H_ + hh) * DH_ * T_;
      #pragma unroll
      for (int mi = 0; mi < MI; ++mi) {
        const int tb = trow0 + mi * 16 + g * 4;
        #pragma unroll
        for (int ni = 0; ni < 4; ++ni) {
          const int dh = ni * 16 + l15;
          unsigned* dst32 = (unsigned*)&vt[vhead + (size_t)dh * T_ + tb];
          dst32[0] = pkbf(acc[mi][ni][0], acc[mi][ni][1]);
          dst32[1] = pkbf(acc[mi][ni][2], acc[mi][ni][3]);
        }
      }
    } else {
      const float cc = cosf(phase[hh]);
      const float ssn = sinf(phase[hh]);
      // Q carries 1/sqrt(DH) and log2(e): scores land in exp2 domain.
      const float qs = (section == 0) ? 0.125f * 1.44269504088896341f : 1.0f;
      bfbits* dst = (section == 0) ? bo0 : bo1;
      const size_t head = (size_t)(b * H_ + hh) * T_ * DH_;
      #pragma unroll
      for (int mi = 0; mi < MI; ++mi) {
        const int tb = trow0 + mi * 16 + g * 4;
        float gv[4];
        #pragma unroll
        for (int r = 0; r < 4; ++r) gv[r] = gate[(size_t)b * T_ + tb + r] * qs;
        #pragma unroll
        for (int ni = 0; ni < 2; ++ni) {
          const int dh = ni * 16 + l15;
          #pragma unroll
          for (int r = 0; r < 4; ++r) {
            const float re = acc[mi][ni][r];
            const float im = acc[mi][ni + 2][r];
            const size_t idx = head + (size_t)(tb + r) * DH_ + dh;
            dst[idx]      = f2bf((re * cc - im * ssn) * gv[r]);
            dst[idx + 32] = f2bf((re * ssn + im * cc) * gv[r]);
          }
        }
      }
    }
  } else if constexpr (EPI == 1) {
    const float* gate = p0;
    const float* x1 = fo1;
    float* x2 = fo0;
    #pragma unroll
    for (int mi = 0; mi < MI; ++mi) {
      const int m = m0 + wr * (MI * 16) + mi * 16 + g * 4;
      float gv[4];
      #pragma unroll
      for (int r = 0; r < 4; ++r) gv[r] = gate[m + r];
      #pragma unroll
      for (int ni = 0; ni < 4; ++ni) {
        const int n = n0 + wc * 64 + ni * 16 + l15;
        #pragma unroll
        for (int r = 0; r < 4; ++r) {
          const size_t idx = (size_t)(m + r) * D_ + n;
          x2[idx] = x1[idx] + acc[mi][ni][r] * gv[r];
        }
      }
    }
  } else if constexpr (EPI == 2) {
    const float* upb = p0;
    bfbits* outm = bo0;
    #pragma unroll
    for (int mi = 0; mi < MI; ++mi) {
      const int m = m0 + wr * (MI * 16) + mi * 16 + g * 4;
      #pragma unroll
      for (int ni = 0; ni < 4; ++ni) {
        const int n = n0 + wc * 64 + ni * 16 + l15;
        const float bb = upb[n < DFF_ ? n : DFF_ - 1];
        #pragma unroll
        for (int r = 0; r < 4; ++r) {
          float v = acc[mi][ni][r] + bb;
          v = 0.5f * v * (1.0f + erff(v * 0.70710678118654752f));
          outm[(size_t)(m + r) * DFFP_ + n] = f2bf(v);
        }
      }
    }
  } else {
    const float* dnb = p0;
    const float* gate = p1;
    const float* cmt = p2;
    const float* x2 = fo1;
    float* outx = fo0;
    const float cb = cmt[b];
    #pragma unroll
    for (int mi = 0; mi < MI; ++mi) {
      const int m = m0 + wr * (MI * 16) + mi * 16 + g * 4;
      float kv[4];
      #pragma unroll
      for (int r = 0; r < 4; ++r) kv[r] = cb * gate[m + r];
      #pragma unroll
      for (int ni = 0; ni < 4; ++ni) {
        const int n = n0 + wc * 64 + ni * 16 + l15;
        const float bb = dnb[n];
        #pragma unroll
        for (int r = 0; r < 4; ++r) {
          const size_t idx = (size_t)(m + r) * D_ + n;
          outx[idx] = x2[idx] + kv[r] * (acc[mi][ni][r] + bb);
        }
      }
    }
  }
}

// ---------- flash attention v7: 32x32x16 MFMA; shfl-based cross-half exchange.
// 1024 blocks x 2 waves; wave owns 32 q-rows; KVBLK=64. Balanced qt map.
// S^T = K*Q^T (col=q=lane&31, row k via crow=(r&3)+8*(r>>2)+4*hi).
// P-pack: per 16-k subtile, lane sends (hi?A:B), partner receives what it
// needs -> 2 shfl_xor(32) per subtile; B-slot k = mf*16 + hi*8 + e.
__global__ void __launch_bounds__(128, 2)
attn_kernel(const bfbits* __restrict__ Qb, const bfbits* __restrict__ Kb,
            const bfbits* __restrict__ Vt, bfbits* __restrict__ AO) {
  __shared__ bfbits Kl[2][64 * 64];   // [k row][dh], chunk-swizzled
  __shared__ bfbits Vl[2][64 * 64];   // [dh row][k], chunk-swizzled
  const int pid = blockIdx.x;         // 0..1023
  const int bh = pid & 31;
  const int j = (pid >> 5) & 7;
  const int slot = pid >> 8;          // 0..3
  const int qt = (slot == 0) ? 31 - j
               : (slot == 1) ? 16 + j
               : (slot == 2) ? 15 - j : j;
  const int qb0 = qt * 64;
  const int tid = threadIdx.x, lane = tid & 63, wq = tid >> 6;
  const int l31 = lane & 31, hi = lane >> 5;
  const int qw = qb0 + wq * 32;       // wave q base

  const bfbits* Qp = Qb + ((size_t)bh * T_ + qw) * DH_;
  const bfbits* Kp = Kb + (size_t)bh * T_ * DH_;
  const bfbits* Vp = Vt + (size_t)bh * DH_ * T_;

  // Q fragments (B-operand): lane l -> Q[qw + l31][mf*16 + hi*8 + e]
  s16x8 qf[4];
  #pragma unroll
  for (int mf = 0; mf < 4; ++mf)
    qf[mf] = *(const s16x8*)(Qp + l31 * DH_ + mf * 16 + hi * 8);

  f32x16 o0 = {}, o1 = {};            // O^T[dh][q], dh-halves 0..31 / 32..63
  float mrun = -INFINITY, lrun = 0.f;
  const int nk = qt + 1;

  // staging: chunk c = i*128+tid; row=c>>3; src col chunk = (c&7)^(row&7)
  const bfbits* kg[4];
  const bfbits* vg[4];
  int cb_[4];
  #pragma unroll
  for (int i = 0; i < 4; ++i) {
    const int c = i * 128 + tid;
    const int row = c >> 3;
    const int sc = ((c & 7) ^ (row & 7)) * 8;
    kg[i] = Kp + row * DH_ + sc;
    vg[i] = Vp + (size_t)row * T_ + sc;
    cb_[i] = c * 16;
  }
  auto stage = [&](int k0, int p) {
    #pragma unroll
    for (int i = 0; i < 4; ++i) {
      gload16(kg[i] + (size_t)k0 * DH_, (char*)&Kl[p][0] + cb_[i]);
      gload16(vg[i] + k0,               (char*)&Vl[p][0] + cb_[i]);
    }
  };

  stage(0, 0);
  __syncthreads();

  for (int t = 0; t < nk; ++t) {
    const int p = t & 1;
    if (t + 1 < nk) stage((t + 1) << 6, p ^ 1);
    // ---- QK^T: S^T[64k][32q], two 32x32 halves ----
    f32x16 s0 = {}, s1 = {};
    __builtin_amdgcn_s_setprio(1);
    #pragma unroll
    for (int mf = 0; mf < 4; ++mf) {
      const int ch = ((mf * 2 + hi) ^ (l31 & 7)) * 8;
      const s16x8 ka  = *(const s16x8*)&Kl[p][l31 * 64 + ch];
      const s16x8 kb2 = *(const s16x8*)&Kl[p][(32 + l31) * 64 + ch];
      s0 = __builtin_amdgcn_mfma_f32_32x32x16_bf16(ka,  qf[mf], s0, 0, 0, 0);
      s1 = __builtin_amdgcn_mfma_f32_32x32x16_bf16(kb2, qf[mf], s1, 0, 0, 0);
    }
    __builtin_amdgcn_s_setprio(0);
    // ---- causal mask (only diagonal = last tile) ----
    if (t == nk - 1) {
      const int qd = wq * 32 + l31;       // q - k0
      #pragma unroll
      for (int r = 0; r < 16; ++r) {
        const int krow = (r & 3) + 8 * (r >> 2) + 4 * hi;
        if (krow > qd)      s0[r] = -1e9f;
        if (krow + 32 > qd) s1[r] = -1e9f;
      }
    }
    // ---- online softmax (exp2 domain), in-lane tree + 1 shfl ----
    float red[8];
    #pragma unroll
    for (int i = 0; i < 8; ++i)
      red[i] = fmaxf(fmaxf(s0[i], s0[i + 8]), fmaxf(s1[i], s1[i + 8]));
    #pragma unroll
    for (int i = 0; i < 4; ++i) red[i] = fmaxf(red[i], red[i + 4]);
    float mx = fmaxf(fmaxf(red[0], red[1]), fmaxf(red[2], red[3]));
    mx = fmaxf(mx, __shfl_xor(mx, 32));
    const bool need = __any(mx > mrun + 8.f) != 0;   // defer-max
    const float mnew = need ? fmaxf(mrun, mx) : mrun;
    s0 = s0 - mnew;
    s1 = s1 - mnew;
    #pragma unroll
    for (int i = 0; i < 16; ++i) { s0[i] = vexp2(s0[i]); s1[i] = vexp2(s1[i]); }
    float sr[8];
    #pragma unroll
    for (int i = 0; i < 8; ++i)
      sr[i] = (s0[i] + s0[i + 8]) + (s1[i] + s1[i + 8]);
    #pragma unroll
    for (int i = 0; i < 4; ++i) sr[i] += sr[i + 4];
    float sum = (sr[0] + sr[1]) + (sr[2] + sr[3]);
    sum += __shfl_xor(sum, 32);
    if (need) {
      const float alpha = vexp2(mrun - mnew);
      mrun = mnew;
      lrun = lrun * alpha + sum;
      o0 *= alpha;
      o1 *= alpha;
    } else {
      lrun += sum;
    }
    // ---- pack P subtiles + PV (O^T += V^T * P^T) ----
    // B-slot k = mf*16 + hi*8 + e. k -> (reg,hi') via k = (r&3)+8*(r>>2)+4hi'.
    // lo lanes need own A0/A1 (w0/w1) + partner A0/A1 (w2/w3);
    // hi lanes need partner B0/B1 (w0/w1) + own B0/B1 (w2/w3).
    #pragma unroll
    for (int mf = 0; mf < 4; ++mf) {
      const f32x16& s = (mf < 2) ? s0 : s1;
      const int r0 = (mf & 1) * 8;
      const unsigned A0 = pkbf(s[r0 + 0], s[r0 + 1]);
      const unsigned A1 = pkbf(s[r0 + 2], s[r0 + 3]);
      const unsigned B0 = pkbf(s[r0 + 4], s[r0 + 5]);
      const unsigned B1 = pkbf(s[r0 + 6], s[r0 + 7]);
      const unsigned x0 = (unsigned)__shfl_xor((int)(hi ? A0 : B0), 32);
      const unsigned x1 = (unsigned)__shfl_xor((int)(hi ? A1 : B1), 32);
      uint4 wv;
      wv.x = hi ? x0 : A0;
      wv.y = hi ? x1 : A1;
      wv.z = hi ? B0 : x0;
      wv.w = hi ? B1 : x1;
      const s16x8 pf = __builtin_bit_cast(s16x8, wv);
      const int ch = ((mf * 2 + hi) ^ (l31 & 7)) * 8;
      const s16x8 v0 = *(const s16x8*)&Vl[p][l31 * 64 + ch];
      const s16x8 v1 = *(const s16x8*)&Vl[p][(32 + l31) * 64 + ch];
      __builtin_amdgcn_s_setprio(1);
      o0 = __builtin_amdgcn_mfma_f32_32x32x16_bf16(v0, pf, o0, 0, 0, 0);
      o1 = __builtin_amdgcn_mfma_f32_32x32x16_bf16(v1, pf, o1, 0, 0, 0);
      __builtin_amdgcn_s_setprio(0);
    }
    __syncthreads();
  }

  // ---- epilogue: O^T reg r -> dh = (r&3)+8*(r>>2)+4*hi, col q = l31 ----
  const float inv = 1.0f / lrun;
  const int q = qw + l31;
  bfbits* dst = AO + ((size_t)(bh >> 4) * T_ + q) * D_ + (bh & 15) * DH_;
  #pragma unroll
  for (int rp = 0; rp < 8; ++rp) {
    const int dh = ((2 * rp) & 3) + 8 * (rp >> 1) + 4 * hi;
    *(unsigned*)(dst + dh)      = pkbf(o0[2 * rp] * inv, o0[2 * rp + 1] * inv);
    *(unsigned*)(dst + 32 + dh) = pkbf(o1[2 * rp] * inv, o1[2 * rp + 1] * inv);
  }
}

// ---------- pooling / commit ----------
__global__ __launch_bounds__(256)
void pool_part(const float* __restrict__ x2, float* __restrict__ part) {
  const int s = blockIdx.x, b = blockIdx.y, tid = threadIdx.x;
  const float* base = x2 + ((size_t)b * T_ + s * 32) * D_ + tid * 4;
  float ax = 0, ay = 0, az = 0, aw = 0;
  #pragma unroll 4
  for (int t = 0; t < 32; ++t) {
    float4 v = *(const float4*)(base + (size_t)t * D_);
    ax += v.x; ay += v.y; az += v.z; aw += v.w;
  }
  float4 ov; ov.x = ax; ov.y = ay; ov.z = az; ov.w = aw;
  *(float4*)(part + (size_t)(b * 64 + s) * D_ + tid * 4) = ov;
}

__global__ __launch_bounds__(256)
void pool_fin(const float* __restrict__ part, float* __restrict__ pool) {
  const int idx = blockIdx.x * 256 + threadIdx.x; // 0..2047
  const int b = idx >> 10, d = idx & 1023;
  float s = 0.f;
  #pragma unroll 8
  for (int i = 0; i < 64; ++i) s += part[(size_t)(b * 64 + i) * D_ + d];
  pool[idx] = s * (1.0f / 2048.0f);
}

__global__ __launch_bounds__(256)
void commit_kernel(const float* __restrict__ pool, const float* __restrict__ cw,
                   const float* __restrict__ cb0, float* __restrict__ cmt,
                   float* __restrict__ out_cmt) {
  const int b = blockIdx.x, tid = threadIdx.x;
  float4 p = *(const float4*)(pool + b * 1024 + tid * 4);
  float4 w = *(const float4*)(cw + tid * 4);
  float s = p.x * w.x + p.y * w.y + p.z * w.z + p.w * w.w;
  #pragma unroll
  for (int o = 32; o > 0; o >>= 1) s += __shfl_xor(s, o);
  __shared__ float ls[4];
  if ((tid & 63) == 0) ls[tid >> 6] = s;
  __syncthreads();
  if (tid == 0) {
    const float t = ls[0] + ls[1] + ls[2] + ls[3] + cb0[0];
    const float v = 1.0f / (1.0f + expf(-t));
    cmt[b] = v; out_cmt[b] = v;
  }
}

// ---------------- host launcher ----------------
extern "C" void kernel_launch(void* const* d_in, const int* in_sizes, int n_in,
                              void* d_out, int out_size, void* d_ws, size_t ws_size,
                              hipStream_t stream) {
  (void)in_sizes; (void)n_in; (void)out_size; (void)ws_size;
  const float* x       = (const float*)d_in[0];
  const float* cfa     = (const float*)d_in[1];
  const float* gate_w  = (const float*)d_in[3];
  const float* gate_b  = (const float*)d_in[4];
  const float* cb_w    = (const float*)d_in[5];
  const float* nf_g    = (const float*)d_in[6];
  const float* nf_b    = (const float*)d_in[7];
  const float* wq      = (const float*)d_in[8];
  const float* wk      = (const float*)d_in[9];
  const float* wv      = (const float*)d_in[10];
  const float* wo      = (const float*)d_in[11];
  const float* phase   = (const float*)d_in[12];
  const float* nb_g    = (const float*)d_in[13];
  const float* nb_b    = (const float*)d_in[14];
  const float* up_w    = (const float*)d_in[15];
  const float* up_b    = (const float*)d_in[16];
  const float* dn_w    = (const float*)d_in[17];
  const float* dn_b    = (const float*)d_in[18];
  const float* cmt_w   = (const float*)d_in[19];
  const float* cmt_b   = (const float*)d_in[20];
  const float* cproj_w = (const float*)d_in[21];
  const float* cproj_b = (const float*)d_in[22];
  const float* bcast_w = (const float*)d_in[23];
  const float* bcast_b = (const float*)d_in[24];

  char* ws = (char*)d_ws;
  float*  x1     = (float*)(ws + OFF_X1);
  bfbits* h      = (bfbits*)(ws + OFF_H);
  bfbits* h2     = (bfbits*)(ws + OFF_H);     // alias: h dead after QKV
  bfbits* qb     = (bfbits*)(ws + OFF_Q);
  bfbits* kb     = (bfbits*)(ws + OFF_K);
  bfbits* vt     = (bfbits*)(ws + OFF_VT);
  bfbits* ffmid  = (bfbits*)(ws + OFF_Q);     // alias: Q/K dead after attention
  bfbits* ao     = (bfbits*)(ws + OFF_AO);
  float*  x2     = (float*)(ws + OFF_X2);
  bfbits* wqkv_t = (bfbits*)(ws + OFF_WQKV);
  bfbits* wo_t   = (bfbits*)(ws + OFF_WO);
  bfbits* wup_t  = (bfbits*)(ws + OFF_WUP);
  bfbits* wdn_t  = (bfbits*)(ws + OFF_WDN);
  float*  bvec   = (float*)(ws + OFF_BVEC);
  float*  cbv    = (float*)(ws + OFF_CBV);
  float*  gate   = (float*)(ws + OFF_GATE);
  float*  part   = (float*)(ws + OFF_PART);
  float*  pool   = (float*)(ws + OFF_POOL);
  float*  cmt    = (float*)(ws + OFF_CMT);

  float* outx   = (float*)d_out;
  float* outc   = outx + NELEM_X;          // center [B][DC]
  float* outg   = outc + B_ * DC_;         // gate [B][T]
  float* outcmt = outg + B_ * T_;          // commit [B]

  // weight prep (B^T bf16)
  transpose_w<<<dim3(32, 32), 256, 0, stream>>>(wq, wqkv_t,                1024, 1024, 1024, 1024);
  transpose_w<<<dim3(32, 32), 256, 0, stream>>>(wk, wqkv_t + 1024 * 1024,  1024, 1024, 1024, 1024);
  transpose_w<<<dim3(32, 32), 256, 0, stream>>>(wv, wqkv_t + 2048 * 1024,  1024, 1024, 1024, 1024);
  transpose_w<<<dim3(32, 32), 256, 0, stream>>>(wo, wo_t,                  1024, 1024, 1024, 1024);
  transpose_w<<<dim3(32, 52), 256, 0, stream>>>(up_w, wup_t,               1024, DFF_, 1024, DFFP_);
  transpose_w<<<dim3(52, 32), 256, 0, stream>>>(dn_w, wdn_t,               DFF_, 1024, DFFP_, 1024);

  gemv_t<<<dim3(32, B_), 256, 0, stream>>>(cfa, bcast_w, bcast_b, bvec, 0);
  cb_kernel<<<B_, 256, 0, stream>>>(cfa, cb_w, cbv);

  ln1_kernel<<<MTOT, 256, 0, stream>>>(x, bvec, cbv, gate_w, gate_b, nf_g, nf_b,
                                       x1, h, gate, outg);

  gemm_bt<0, 128><<<dim3(24, 32), 256, 0, stream>>>(
      h, 1024, wqkv_t, 1024, 1024, gate, phase, nullptr,
      nullptr, nullptr, qb, kb, vt);

  attn_kernel<<<1024, 128, 0, stream>>>(qb, kb, vt, ao);

  gemm_bt<1, 64><<<dim3(8, 64), 256, 0, stream>>>(
      ao, 1024, wo_t, 1024, 1024, gate, nullptr, nullptr,
      x2, x1, nullptr, nullptr, nullptr);

  ln2_kernel<<<MTOT, 256, 0, stream>>>(x2, nb_g, nb_b, h2);

  // pooled stats only need x2 -> run before FF so DN can fuse the final add
  pool_part<<<dim3(64, B_), 256, 0, stream>>>(x2, part);
  pool_fin<<<8, 256, 0, stream>>>(part, pool);
  commit_kernel<<<B_, 256, 0, stream>>>(pool, cmt_w, cmt_b, cmt, outcmt);
  gemv_t<<<dim3(32, B_), 256, 0, stream>>>(pool, cproj_w, cproj_b, outc, 1);

  gemm_bt<2, 64><<<dim3(13, 64), 256, 0, stream>>>(
      h2, 1024, wup_t, 1024, 1024, up_b, nullptr, nullptr,
      nullptr, nullptr, ffmid, nullptr, nullptr);

  gemm_bt<3, 64><<<dim3(8, 64), 256, 0, stream>>>(
      ffmid, DFFP_, wdn_t, DFFP_, DFFP_, dn_b, gate, cmt,
      outx, x2, nullptr, nullptr, nullptr);
}

// Round 8
// 238.560 us; speedup vs baseline: 1.1418x; 1.0825x over previous
//
#include <hip/hip_runtime.h>
#include <math.h>

// ---- problem constants ----
#define B_   2
#define T_   2048
#define D_   1024
#define H_   16
#define DH_  64
#define DC_  1024
#define DFF_ 1656
#define DFFP_ 1664
#define MTOT 4096          // B_*T_
#define NELEM_X 4194304ull // B*T*D

typedef short s16x8 __attribute__((ext_vector_type(8)));
typedef unsigned short u16x4 __attribute__((ext_vector_type(4)));
typedef float f32x4 __attribute__((ext_vector_type(4)));
typedef float f32x16 __attribute__((ext_vector_type(16)));
typedef unsigned short bfbits;

__device__ __forceinline__ bfbits f2bf(float f) {
  unsigned int u = __builtin_bit_cast(unsigned int, f);
  u += 0x7fffu + ((u >> 16) & 1u);          // RNE
  return (bfbits)(u >> 16);
}

__device__ __forceinline__ float vexp2(float x) {   // 2^x via HW transcendental
  float r;
  asm("v_exp_f32 %0, %1" : "=v"(r) : "v"(x));
  return r;
}
__device__ __forceinline__ unsigned pkbf(float lo, float hi) { // 2xbf16 pack, RNE
  unsigned r;
  asm("v_cvt_pk_bf16_f32 %0, %1, %2" : "=v"(r) : "v"(lo), "v"(hi));
  return r;
}

__device__ __forceinline__ void gload16(const void* g, void* l) {
  __builtin_amdgcn_global_load_lds(
      (__attribute__((address_space(1))) void*)g,
      (__attribute__((address_space(3))) void*)l, 16, 0, 0);
}

// ---------- workspace offsets (bytes) ----------
constexpr size_t OFF_X1   = 0;                                  // f32 x1
constexpr size_t OFF_H    = OFF_X1 + 4ull*NELEM_X;              // bf16 h ; later h2
constexpr size_t OFF_Q    = OFF_H  + 2ull*NELEM_X;              // bf16 Q [BH][T][64] ; later ffmid
constexpr size_t OFF_K    = OFF_Q  + 2ull*NELEM_X;              // bf16 K [BH][T][64]
constexpr size_t OFF_VT   = OFF_K  + 2ull*NELEM_X;              // bf16 V^T [BH][64][T]
constexpr size_t OFF_AO   = OFF_VT + 2ull*NELEM_X;              // bf16 attn out [M][D]
constexpr size_t OFF_X2   = OFF_AO + 2ull*NELEM_X;              // f32 x2; pO alias during attn
constexpr size_t OFF_WQKV = OFF_X2 + 4ull*NELEM_X;              // bf16 [3072][1024]
constexpr size_t OFF_WO   = OFF_WQKV + 3072ull*1024*2;          // bf16 [1024][1024]
constexpr size_t OFF_WUP  = OFF_WO   + 1024ull*1024*2;          // bf16 [1664][1024]
constexpr size_t OFF_WDN  = OFF_WUP  + 1664ull*1024*2;          // bf16 [1024][1664]
constexpr size_t OFF_BVEC = OFF_WDN  + 1024ull*1664*2;          // f32 [B][D]
constexpr size_t OFF_CBV  = OFF_BVEC + 2048ull*4;               // f32 [B]
constexpr size_t OFF_GATE = OFF_CBV  + 256;                     // f32 [M]
constexpr size_t OFF_PART = OFF_GATE + 4096ull*4;               // f32 [128][1024]
constexpr size_t OFF_POOL = OFF_PART + 128ull*1024*4;           // f32 [B][D]
constexpr size_t OFF_CMT  = OFF_POOL + 2048ull*4;               // f32 [B]
constexpr size_t OFF_PM   = OFF_CMT  + 256;                     // f32 [1024][64]
constexpr size_t OFF_PL   = OFF_PM   + 1024ull*64*4;            // f32 [1024][64]

// attention job table: 8 groups (j) x 6 slots; entry = qt | kind<<8
// kind: 0 = full (L), 1 = k-range [0,mid) (A), 2 = k-range [mid,nk) (B)
// every group's 6 jobs sum to exactly 66 k-tiles; max job = 16 tiles.
__constant__ unsigned short JOBS[8][6] = {
  {0x00F, 0x11C, 0x11A, 0x118, 0x006, 0x000},
  {0x11E, 0x11D, 0x11B, 0x119, 0x005, 0x001},
  {0x11F, 0x21D, 0x21B, 0x219, 0x004, 0x002},
  {0x21F, 0x21C, 0x00B, 0x114, 0x008, 0x003},
  {0x21E, 0x00C, 0x116, 0x009, 0x007, 0x210},
  {0x00E, 0x117, 0x217, 0x110, 0x111, 0x211},
  {0x00D, 0x218, 0x115, 0x112, 0x213, 0x212},
  {0x21A, 0x215, 0x216, 0x00A, 0x113, 0x214},
};

// ---------- transpose f32 [R][C] -> bf16 [Npad][Rpad]
__global__ __launch_bounds__(256)
void transpose_w(const float* __restrict__ src, bfbits* __restrict__ dst,
                 int R, int C, int Rpad, int Npad) {
  __shared__ float tile[32][33];
  const int kb = blockIdx.x * 32, nb = blockIdx.y * 32;
  const int tx = threadIdx.x & 31, ty = threadIdx.x >> 5;
  for (int i = ty; i < 32; i += 8) {
    const int k = kb + i, n = nb + tx;
    tile[i][tx] = (k < R && n < C) ? src[(size_t)k * C + n] : 0.f;
  }
  __syncthreads();
  for (int i = ty; i < 32; i += 8) {
    const int n = nb + i, k = kb + tx;
    if (n < Npad && k < Rpad) dst[(size_t)n * Rpad + k] = f2bf(tile[tx][i]);
  }
}

// ---------- GEMV: out[b][d] = f(vec[b] @ w[.][d] + bias[d])
__global__ __launch_bounds__(256)
void gemv_t(const float* __restrict__ v, const float* __restrict__ w,
            const float* __restrict__ bias, float* __restrict__ out,
            int tanh_mode) {
  const int b = blockIdx.y;
  const int dl = threadIdx.x & 31, cl = threadIdx.x >> 5;
  const int d = blockIdx.x * 32 + dl;
  const float* vb = v + b * 1024;
  float s = 0.f;
  #pragma unroll 4
  for (int c = cl; c < 1024; c += 8)
    s += vb[c] * w[(size_t)c * 1024 + d];
  __shared__ float red[8][32];
  red[cl][dl] = s;
  __syncthreads();
  if (threadIdx.x < 32) {
    float t = 0.f;
    #pragma unroll
    for (int i = 0; i < 8; ++i) t += red[i][threadIdx.x];
    const int dd = blockIdx.x * 32 + threadIdx.x;
    t += bias[dd];
    out[b * 1024 + dd] = tanh_mode ? tanhf(t) : t;
  }
}

__global__ __launch_bounds__(256)
void cb_kernel(const float* __restrict__ cfa, const float* __restrict__ cbw,
               float* __restrict__ cbv) {
  const int b = blockIdx.x, tid = threadIdx.x;
  float4 a = *(const float4*)(cfa + b * 1024 + tid * 4);
  float4 w = *(const float4*)(cbw + tid * 4);
  float s = a.x * w.x + a.y * w.y + a.z * w.z + a.w * w.w;
  #pragma unroll
  for (int o = 32; o > 0; o >>= 1) s += __shfl_xor(s, o);
  __shared__ float ls[4];
  if ((tid & 63) == 0) ls[tid >> 6] = s;
  __syncthreads();
  if (tid == 0) cbv[b] = ls[0] + ls[1] + ls[2] + ls[3];
}

__device__ __forceinline__ void blockreduce3(float& a, float& b, float& c) {
  #pragma unroll
  for (int o = 32; o > 0; o >>= 1) {
    a += __shfl_xor(a, o);
    b += __shfl_xor(b, o);
    c += __shfl_xor(c, o);
  }
  __shared__ float ls[3][4];
  const int lane = threadIdx.x & 63, w = threadIdx.x >> 6;
  if (lane == 0) { ls[0][w] = a; ls[1][w] = b; ls[2][w] = c; }
  __syncthreads();
  a = ls[0][0] + ls[0][1] + ls[0][2] + ls[0][3];
  b = ls[1][0] + ls[1][1] + ls[1][2] + ls[1][3];
  c = ls[2][0] + ls[2][1] + ls[2][2] + ls[2][3];
}

// ---------- fused: x1 = x + bvec ; gate ; LN(x1) -> h (bf16)
__global__ __launch_bounds__(256)
void ln1_kernel(const float* __restrict__ x, const float* __restrict__ bvec,
                const float* __restrict__ cbv, const float* __restrict__ gw,
                const float* __restrict__ gb, const float* __restrict__ nfg,
                const float* __restrict__ nfb, float* __restrict__ x1,
                bfbits* __restrict__ h, float* __restrict__ gate_ws,
                float* __restrict__ gate_out) {
  const int m = blockIdx.x, tid = threadIdx.x, b = m >> 11;
  const size_t ro = (size_t)m * D_ + tid * 4;
  float4 xv = *(const float4*)(x + ro);
  float4 bv = *(const float4*)(bvec + b * D_ + tid * 4);
  float4 v;
  v.x = xv.x + bv.x; v.y = xv.y + bv.y; v.z = xv.z + bv.z; v.w = xv.w + bv.w;
  float4 g4 = *(const float4*)(gw + tid * 4);
  float s  = v.x + v.y + v.z + v.w;
  float s2 = v.x*v.x + v.y*v.y + v.z*v.z + v.w*v.w;
  float dg = v.x*g4.x + v.y*g4.y + v.z*g4.z + v.w*g4.w;
  blockreduce3(s, s2, dg);
  const float mean = s * (1.0f/1024.0f);
  const float var  = s2 * (1.0f/1024.0f) - mean*mean;
  const float rstd = rsqrtf(var + 1e-5f);
  if (tid == 0) {
    const float logits = dg + gb[0] + cbv[b];
    const float prob = 1.0f / (1.0f + expf(-logits));
    const float hard = prob > 0.5f ? 1.0f : 0.0f;
    const float gv = (hard - prob) + prob;
    gate_ws[m] = gv; gate_out[m] = gv;
  }
  *(float4*)(x1 + ro) = v;
  float4 gg = *(const float4*)(nfg + tid * 4);
  float4 b2 = *(const float4*)(nfb + tid * 4);
  u16x4 hv;
  hv[0] = f2bf((v.x - mean) * rstd * gg.x + b2.x);
  hv[1] = f2bf((v.y - mean) * rstd * gg.y + b2.y);
  hv[2] = f2bf((v.z - mean) * rstd * gg.z + b2.z);
  hv[3] = f2bf((v.w - mean) * rstd * gg.w + b2.w);
  *(u16x4*)(h + ro) = hv;
}

__global__ __launch_bounds__(256)
void ln2_kernel(const float* __restrict__ x2, const float* __restrict__ gptr,
                const float* __restrict__ bptr, bfbits* __restrict__ h2) {
  const int m = blockIdx.x, tid = threadIdx.x;
  const size_t ro = (size_t)m * D_ + tid * 4;
  float4 v = *(const float4*)(x2 + ro);
  float s  = v.x + v.y + v.z + v.w;
  float s2 = v.x*v.x + v.y*v.y + v.z*v.z + v.w*v.w;
  float d0 = 0.f;
  blockreduce3(s, s2, d0);
  const float mean = s * (1.0f/1024.0f);
  const float var  = s2 * (1.0f/1024.0f) - mean*mean;
  const float rstd = rsqrtf(var + 1e-5f);
  float4 gg = *(const float4*)(gptr + tid * 4);
  float4 b2 = *(const float4*)(bptr + tid * 4);
  u16x4 hv;
  hv[0] = f2bf((v.x - mean) * rstd * gg.x + b2.x);
  hv[1] = f2bf((v.y - mean) * rstd * gg.y + b2.y);
  hv[2] = f2bf((v.z - mean) * rstd * gg.z + b2.z);
  hv[3] = f2bf((v.w - mean) * rstd * gg.w + b2.w);
  *(u16x4*)(h2 + ro) = hv;
}

// ---------- GEMM: C[M][N] = A[M][K](bf16) * Bt[N][K](bf16), double-buffered LDS,
// XOR-swizzled staging (source-side) so ds_read_b128 is ~conflict-free.
// EPI 0: QKV (rope+gate, Q*(1/8)*log2e; V -> V^T)  [BM=128, BK=32]
// EPI 1: WO (x2 = x1 + C*gate)                      [BM=64, BK=64]
// EPI 2: UP (gelu(C+up_b) -> bf16, ldc=1664)        [BM=64, BK=64]
// EPI 3: DN fused final (outx = x2+cmt*gate*(C+b))  [BM=64, BK=64]
template <int EPI, int BM, int BK>
__global__ void __launch_bounds__(256, 2)
gemm_bt(const bfbits* __restrict__ A, int lda,
        const bfbits* __restrict__ Bt, int ldb, int K,
        const float* __restrict__ p0, const float* __restrict__ p1,
        const float* __restrict__ p2,
        float* __restrict__ fo0, const float* __restrict__ fo1,
        bfbits* __restrict__ bo0, bfbits* __restrict__ bo1,
        bfbits* __restrict__ bo2) {
  constexpr int MI = BM / 32;               // m-fragments per wave
  constexpr int RCH = BK / 8;               // 16B chunks per row
  constexpr int NK = BK / 32;               // 32-wide k sub-steps
  __shared__ bfbits Asl[2][BM * BK];
  __shared__ bfbits Bsl[2][128 * BK];
  const int tid = threadIdx.x;
  const int lane = tid & 63, wave = tid >> 6;
  const int g = lane >> 4, l15 = lane & 15;
  const int wr = wave >> 1, wc = wave & 1;
  const int m0 = blockIdx.y * BM, n0 = blockIdx.x * 128;

  auto stage = [&](int k0, int p) {
    #pragma unroll
    for (int i = 0; i < (BM * RCH) / 256; ++i) {
      const int c = i * 256 + tid;
      const int row = c / RCH;
      const int ko = ((c % RCH) ^ (row & (RCH - 1))) * 8;
      gload16(A + (size_t)(m0 + row) * lda + (k0 + ko),
              (char*)&Asl[p][0] + c * 16);
    }
    #pragma unroll
    for (int i = 0; i < (128 * RCH) / 256; ++i) {
      const int c = i * 256 + tid;
      const int row = c / RCH;
      const int ko = ((c % RCH) ^ (row & (RCH - 1))) * 8;
      gload16(Bt + (size_t)(n0 + row) * ldb + (k0 + ko),
              (char*)&Bsl[p][0] + c * 16);
    }
  };

  f32x4 acc[MI][4] = {};
  stage(0, 0);
  __syncthreads();

  int t = 0;
  for (int k0 = 0; k0 < K; k0 += BK, ++t) {
    const int p = t & 1;
    if (k0 + BK < K) stage(k0 + BK, p ^ 1);
    s16x8 af[NK][MI], bfr[NK][4];
    #pragma unroll
    for (int kk = 0; kk < NK; ++kk) {
      #pragma unroll
      for (int i = 0; i < MI; ++i) {
        const int row = wr * (MI * 16) + i * 16 + l15;
        af[kk][i] = *(const s16x8*)&Asl[p][row * BK + (((kk * 4 + g) ^ (row & (RCH - 1))) * 8)];
      }
      #pragma unroll
      for (int i = 0; i < 4; ++i) {
        const int row = wc * 64 + i * 16 + l15;
        bfr[kk][i] = *(const s16x8*)&Bsl[p][row * BK + (((kk * 4 + g) ^ (row & (RCH - 1))) * 8)];
      }
    }
    #pragma unroll
    for (int kk = 0; kk < NK; ++kk)
      #pragma unroll
      for (int i = 0; i < MI; ++i)
        #pragma unroll
        for (int j = 0; j < 4; ++j)
          acc[i][j] = __builtin_amdgcn_mfma_f32_16x16x32_bf16(af[kk][i], bfr[kk][j], acc[i][j], 0, 0, 0);
    __syncthreads();
  }

  const int b = m0 >> 11;
  const int trow0 = (m0 & 2047) + wr * (MI * 16);

  if constexpr (EPI == 0) {
    const float* gate = p0;
    const float* phase = p1;
    const int ncol0 = n0 + wc * 64;
    const int section = ncol0 >> 10;          // 0=Q 1=K 2=V
    const int hh = (ncol0 & 1023) >> 6;
    if (section == 2) {
      bfbits* vt = bo2;
      const size_t vhead = (size_t)(b * H_ + hh) * DH_ * T_;
      #pragma unroll
      for (int mi = 0; mi < MI; ++mi) {
        const int tb = trow0 + mi * 16 + g * 4;
        #pragma unroll
        for (int ni = 0; ni < 4; ++ni) {
          const int dh = ni * 16 + l15;
          unsigned* dst32 = (unsigned*)&vt[vhead + (size_t)dh * T_ + tb];
          dst32[0] = pkbf(acc[mi][ni][0], acc[mi][ni][1]);
          dst32[1] = pkbf(acc[mi][ni][2], acc[mi][ni][3]);
        }
      }
    } else {
      const float cc = cosf(phase[hh]);
      const float ssn = sinf(phase[hh]);
      // Q carries 1/sqrt(DH) and log2(e): scores land in exp2 domain.
      const float qs = (section == 0) ? 0.125f * 1.44269504088896341f : 1.0f;
      bfbits* dst = (section == 0) ? bo0 : bo1;
      const size_t head = (size_t)(b * H_ + hh) * T_ * DH_;
      #pragma unroll
      for (int mi = 0; mi < MI; ++mi) {
        const int tb = trow0 + mi * 16 + g * 4;
        float gv[4];
        #pragma unroll
        for (int r = 0; r < 4; ++r) gv[r] = gate[(size_t)b * T_ + tb + r] * qs;
        #pragma unroll
        for (int ni = 0; ni < 2; ++ni) {
          const int dh = ni * 16 + l15;
          #pragma unroll
          for (int r = 0; r < 4; ++r) {
            const float re = acc[mi][ni][r];
            const float im = acc[mi][ni + 2][r];
            const size_t idx = head + (size_t)(tb + r) * DH_ + dh;
            dst[idx]      = f2bf((re * cc - im * ssn) * gv[r]);
            dst[idx + 32] = f2bf((re * ssn + im * cc) * gv[r]);
          }
        }
      }
    }
  } else if constexpr (EPI == 1) {
    const float* gate = p0;
    const float* x1 = fo1;
    float* x2 = fo0;
    #pragma unroll
    for (int mi = 0; mi < MI; ++mi) {
      const int m = m0 + wr * (MI * 16) + mi * 16 + g * 4;
      float gv[4];
      #pragma unroll
      for (int r = 0; r < 4; ++r) gv[r] = gate[m + r];
      #pragma unroll
      for (int ni = 0; ni < 4; ++ni) {
        const int n = n0 + wc * 64 + ni * 16 + l15;
        #pragma unroll
        for (int r = 0; r < 4; ++r) {
          const size_t idx = (size_t)(m + r) * D_ + n;
          x2[idx] = x1[idx] + acc[mi][ni][r] * gv[r];
        }
      }
    }
  } else if constexpr (EPI == 2) {
    const float* upb = p0;
    bfbits* outm = bo0;
    #pragma unroll
    for (int mi = 0; mi < MI; ++mi) {
      const int m = m0 + wr * (MI * 16) + mi * 16 + g * 4;
      #pragma unroll
      for (int ni = 0; ni < 4; ++ni) {
        const int n = n0 + wc * 64 + ni * 16 + l15;
        const float bb = upb[n < DFF_ ? n : DFF_ - 1];
        #pragma unroll
        for (int r = 0; r < 4; ++r) {
          float v = acc[mi][ni][r] + bb;
          v = 0.5f * v * (1.0f + erff(v * 0.70710678118654752f));
          outm[(size_t)(m + r) * DFFP_ + n] = f2bf(v);
        }
      }
    }
  } else {
    const float* dnb = p0;
    const float* gate = p1;
    const float* cmt = p2;
    const float* x2 = fo1;
    float* outx = fo0;
    const float cb = cmt[b];
    #pragma unroll
    for (int mi = 0; mi < MI; ++mi) {
      const int m = m0 + wr * (MI * 16) + mi * 16 + g * 4;
      float kv[4];
      #pragma unroll
      for (int r = 0; r < 4; ++r) kv[r] = cb * gate[m + r];
      #pragma unroll
      for (int ni = 0; ni < 4; ++ni) {
        const int n = n0 + wc * 64 + ni * 16 + l15;
        const float bb = dnb[n];
        #pragma unroll
        for (int r = 0; r < 4; ++r) {
          const size_t idx = (size_t)(m + r) * D_ + n;
          outx[idx] = x2[idx] + kv[r] * (acc[mi][ni][r] + bb);
        }
      }
    }
  }
}

// ---------- flash attention v8: split-K jobs, all equal-length per CU.
// 1536 blocks x 2 waves; wave owns 32 q-rows; KVBLK=64; single-buffer LDS
// (16KB -> 6 blocks/CU co-resident = 12 waves/CU). Heavy q-tiles (qt>=16)
// split into two k-range partial jobs (m,l,O^T f32 partials), merged after.
__global__ void __launch_bounds__(128, 3)
attn_kernel(const bfbits* __restrict__ Qb, const bfbits* __restrict__ Kb,
            const bfbits* __restrict__ Vt, bfbits* __restrict__ AO,
            float* __restrict__ pm, float* __restrict__ pl,
            float* __restrict__ pO) {
  __shared__ bfbits Kl[64 * 64];   // [k row][dh], chunk-swizzled
  __shared__ bfbits Vl[64 * 64];   // [dh row][k], chunk-swizzled
  const int pid = blockIdx.x;         // 0..1535
  const int bh = pid & 31;
  const int j = (pid >> 5) & 7;
  const int slot = pid >> 8;          // 0..5
  const unsigned job = JOBS[j][slot];
  const int qt = job & 0xFF;
  const int kind = job >> 8;          // 0=L 1=A 2=B
  const int nk = qt + 1;
  const int mid = (nk + 1) >> 1;
  const int t0 = (kind == 2) ? mid : 0;
  const int t1 = (kind == 1) ? mid : nk;
  const int qb0 = qt * 64;
  const int tid = threadIdx.x, lane = tid & 63, wq = tid >> 6;
  const int l31 = lane & 31, hi = lane >> 5;
  const int qw = qb0 + wq * 32;       // wave q base

  const bfbits* Qp = Qb + ((size_t)bh * T_ + qw) * DH_;
  const bfbits* Kp = Kb + (size_t)bh * T_ * DH_;
  const bfbits* Vp = Vt + (size_t)bh * DH_ * T_;

  // Q fragments (B-operand): lane l -> Q[qw + l31][mf*16 + hi*8 + e]
  s16x8 qf[4];
  #pragma unroll
  for (int mf = 0; mf < 4; ++mf)
    qf[mf] = *(const s16x8*)(Qp + l31 * DH_ + mf * 16 + hi * 8);

  f32x16 o0 = {}, o1 = {};            // O^T[dh][q], dh-halves 0..31 / 32..63
  float mrun = -INFINITY, lrun = 0.f;

  // staging: chunk c = i*128+tid; row=c>>3; src col chunk = (c&7)^(row&7)
  const bfbits* kg[4];
  const bfbits* vg[4];
  int cb_[4];
  #pragma unroll
  for (int i = 0; i < 4; ++i) {
    const int c = i * 128 + tid;
    const int row = c >> 3;
    const int sc = ((c & 7) ^ (row & 7)) * 8;
    kg[i] = Kp + row * DH_ + sc;
    vg[i] = Vp + (size_t)row * T_ + sc;
    cb_[i] = c * 16;
  }

  for (int t = t0; t < t1; ++t) {
    const int k0 = t << 6;
    #pragma unroll
    for (int i = 0; i < 4; ++i) {
      gload16(kg[i] + (size_t)k0 * DH_, (char*)&Kl[0] + cb_[i]);
      gload16(vg[i] + k0,               (char*)&Vl[0] + cb_[i]);
    }
    __syncthreads();                  // drains vmcnt -> tiles ready
    // ---- QK^T: S^T[64k][32q], two 32x32 halves ----
    f32x16 s0 = {}, s1 = {};
    __builtin_amdgcn_s_setprio(1);
    #pragma unroll
    for (int mf = 0; mf < 4; ++mf) {
      const int ch = ((mf * 2 + hi) ^ (l31 & 7)) * 8;
      const s16x8 ka  = *(const s16x8*)&Kl[l31 * 64 + ch];
      const s16x8 kb2 = *(const s16x8*)&Kl[(32 + l31) * 64 + ch];
      s0 = __builtin_amdgcn_mfma_f32_32x32x16_bf16(ka,  qf[mf], s0, 0, 0, 0);
      s1 = __builtin_amdgcn_mfma_f32_32x32x16_bf16(kb2, qf[mf], s1, 0, 0, 0);
    }
    __builtin_amdgcn_s_setprio(0);
    // ---- causal mask (only the diagonal tile t == qt) ----
    if (t == qt) {
      const int qd = wq * 32 + l31;       // q - k0
      #pragma unroll
      for (int r = 0; r < 16; ++r) {
        const int krow = (r & 3) + 8 * (r >> 2) + 4 * hi;
        if (krow > qd)      s0[r] = -1e9f;
        if (krow + 32 > qd) s1[r] = -1e9f;
      }
    }
    // ---- online softmax (exp2 domain), in-lane tree + 1 shfl ----
    float red[8];
    #pragma unroll
    for (int i = 0; i < 8; ++i)
      red[i] = fmaxf(fmaxf(s0[i], s0[i + 8]), fmaxf(s1[i], s1[i + 8]));
    #pragma unroll
    for (int i = 0; i < 4; ++i) red[i] = fmaxf(red[i], red[i + 4]);
    float mx = fmaxf(fmaxf(red[0], red[1]), fmaxf(red[2], red[3]));
    mx = fmaxf(mx, __shfl_xor(mx, 32));
    const bool need = __any(mx > mrun + 8.f) != 0;   // defer-max
    const float mnew = need ? fmaxf(mrun, mx) : mrun;
    s0 = s0 - mnew;
    s1 = s1 - mnew;
    #pragma unroll
    for (int i = 0; i < 16; ++i) { s0[i] = vexp2(s0[i]); s1[i] = vexp2(s1[i]); }
    float sr[8];
    #pragma unroll
    for (int i = 0; i < 8; ++i)
      sr[i] = (s0[i] + s0[i + 8]) + (s1[i] + s1[i + 8]);
    #pragma unroll
    for (int i = 0; i < 4; ++i) sr[i] += sr[i + 4];
    float sum = (sr[0] + sr[1]) + (sr[2] + sr[3]);
    sum += __shfl_xor(sum, 32);
    if (need) {
      const float alpha = vexp2(mrun - mnew);
      mrun = mnew;
      lrun = lrun * alpha + sum;
      o0 *= alpha;
      o1 *= alpha;
    } else {
      lrun += sum;
    }
    // ---- pack P subtiles + PV (O^T += V^T * P^T) ----
    #pragma unroll
    for (int mf = 0; mf < 4; ++mf) {
      const f32x16& s = (mf < 2) ? s0 : s1;
      const int r0 = (mf & 1) * 8;
      const unsigned A0 = pkbf(s[r0 + 0], s[r0 + 1]);
      const unsigned A1 = pkbf(s[r0 + 2], s[r0 + 3]);
      const unsigned B0 = pkbf(s[r0 + 4], s[r0 + 5]);
      const unsigned B1 = pkbf(s[r0 + 6], s[r0 + 7]);
      const unsigned x0 = (unsigned)__shfl_xor((int)(hi ? A0 : B0), 32);
      const unsigned x1 = (unsigned)__shfl_xor((int)(hi ? A1 : B1), 32);
      uint4 wv;
      wv.x = hi ? x0 : A0;
      wv.y = hi ? x1 : A1;
      wv.z = hi ? B0 : x0;
      wv.w = hi ? B1 : x1;
      const s16x8 pf = __builtin_bit_cast(s16x8, wv);
      const int ch = ((mf * 2 + hi) ^ (l31 & 7)) * 8;
      const s16x8 v0 = *(const s16x8*)&Vl[l31 * 64 + ch];
      const s16x8 v1 = *(const s16x8*)&Vl[(32 + l31) * 64 + ch];
      __builtin_amdgcn_s_setprio(1);
      o0 = __builtin_amdgcn_mfma_f32_32x32x16_bf16(v0, pf, o0, 0, 0, 0);
      o1 = __builtin_amdgcn_mfma_f32_32x32x16_bf16(v1, pf, o1, 0, 0, 0);
      __builtin_amdgcn_s_setprio(0);
    }
    __syncthreads();                  // all reads done before next overwrite
  }

  if (kind == 0) {
    // ---- direct epilogue: reg r -> dh = (r&3)+8*(r>>2)+4*hi, col q = l31 ----
    const float inv = 1.0f / lrun;
    const int q = qw + l31;
    bfbits* dst = AO + ((size_t)(bh >> 4) * T_ + q) * D_ + (bh & 15) * DH_;
    #pragma unroll
    for (int rp = 0; rp < 8; ++rp) {
      const int dh = ((2 * rp) & 3) + 8 * (rp >> 1) + 4 * hi;
      *(unsigned*)(dst + dh)      = pkbf(o0[2 * rp] * inv, o0[2 * rp + 1] * inv);
      *(unsigned*)(dst + 32 + dh) = pkbf(o1[2 * rp] * inv, o1[2 * rp + 1] * inv);
    }
  } else {
    // ---- partial epilogue: store m, l, unnormalized O^T (f32) ----
    const int jid = ((qt - 16) * 32 + bh) * 2 + (kind - 1);
    const int qloc = wq * 32 + l31;
    pm[jid * 64 + qloc] = mrun;
    pl[jid * 64 + qloc] = lrun;
    float* po = pO + (size_t)jid * 4096;
    #pragma unroll
    for (int r = 0; r < 16; ++r) {
      const int dh = (r & 3) + 8 * (r >> 2) + 4 * hi;
      po[dh * 64 + qloc]        = o0[r];
      po[(dh + 32) * 64 + qloc] = o1[r];
    }
  }
}

// ---------- merge split-K attention partials (qt 16..31) ----------
__global__ void __launch_bounds__(64)
attn_merge(const float* __restrict__ pm, const float* __restrict__ pl,
           const float* __restrict__ pO, bfbits* __restrict__ AO) {
  __shared__ float lds[64][65];
  const int u = blockIdx.x;             // 0..511
  const int qt = 16 + (u >> 5), bh = u & 31;
  const int q = threadIdx.x;            // 0..63
  const int jA = ((qt - 16) * 32 + bh) * 2, jB = jA + 1;
  const float mA = pm[jA * 64 + q], mB = pm[jB * 64 + q];
  const float lA = pl[jA * 64 + q], lB = pl[jB * 64 + q];
  const float m = fmaxf(mA, mB);
  const float eA = vexp2(mA - m), eB = vexp2(mB - m);
  const float inv = 1.0f / (lA * eA + lB * eB);
  const float* OA = pO + (size_t)jA * 4096;
  const float* OB = pO + (size_t)jB * 4096;
  for (int dh = 0; dh < 64; ++dh)
    lds[dh][q] = (OA[dh * 64 + q] * eA + OB[dh * 64 + q] * eB) * inv;
  __syncthreads();
  const int b = bh >> 4, hh = bh & 15;
  bfbits* dst = AO + ((size_t)b * T_ + qt * 64) * D_ + hh * DH_ + q; // thread=dh col
  for (int qq = 0; qq < 64; ++qq)
    dst[(size_t)qq * D_] = f2bf(lds[q][qq]);
}

// ---------- pooling / commit ----------
__global__ __launch_bounds__(256)
void pool_part(const float* __restrict__ x2, float* __restrict__ part) {
  const int s = blockIdx.x, b = blockIdx.y, tid = threadIdx.x;
  const float* base = x2 + ((size_t)b * T_ + s * 32) * D_ + tid * 4;
  float ax = 0, ay = 0, az = 0, aw = 0;
  #pragma unroll 4
  for (int t = 0; t < 32; ++t) {
    float4 v = *(const float4*)(base + (size_t)t * D_);
    ax += v.x; ay += v.y; az += v.z; aw += v.w;
  }
  float4 ov; ov.x = ax; ov.y = ay; ov.z = az; ov.w = aw;
  *(float4*)(part + (size_t)(b * 64 + s) * D_ + tid * 4) = ov;
}

__global__ __launch_bounds__(256)
void pool_fin(const float* __restrict__ part, float* __restrict__ pool) {
  const int idx = blockIdx.x * 256 + threadIdx.x; // 0..2047
  const int b = idx >> 10, d = idx & 1023;
  float s = 0.f;
  #pragma unroll 8
  for (int i = 0; i < 64; ++i) s += part[(size_t)(b * 64 + i) * D_ + d];
  pool[idx] = s * (1.0f / 2048.0f);
}

__global__ __launch_bounds__(256)
void commit_kernel(const float* __restrict__ pool, const float* __restrict__ cw,
                   const float* __restrict__ cb0, float* __restrict__ cmt,
                   float* __restrict__ out_cmt) {
  const int b = blockIdx.x, tid = threadIdx.x;
  float4 p = *(const float4*)(pool + b * 1024 + tid * 4);
  float4 w = *(const float4*)(cw + tid * 4);
  float s = p.x * w.x + p.y * w.y + p.z * w.z + p.w * w.w;
  #pragma unroll
  for (int o = 32; o > 0; o >>= 1) s += __shfl_xor(s, o);
  __shared__ float ls[4];
  if ((tid & 63) == 0) ls[tid >> 6] = s;
  __syncthreads();
  if (tid == 0) {
    const float t = ls[0] + ls[1] + ls[2] + ls[3] + cb0[0];
    const float v = 1.0f / (1.0f + expf(-t));
    cmt[b] = v; out_cmt[b] = v;
  }
}

// ---------------- host launcher ----------------
extern "C" void kernel_launch(void* const* d_in, const int* in_sizes, int n_in,
                              void* d_out, int out_size, void* d_ws, size_t ws_size,
                              hipStream_t stream) {
  (void)in_sizes; (void)n_in; (void)out_size; (void)ws_size;
  const float* x       = (const float*)d_in[0];
  const float* cfa     = (const float*)d_in[1];
  const float* gate_w  = (const float*)d_in[3];
  const float* gate_b  = (const float*)d_in[4];
  const float* cb_w    = (const float*)d_in[5];
  const float* nf_g    = (const float*)d_in[6];
  const float* nf_b    = (const float*)d_in[7];
  const float* wq      = (const float*)d_in[8];
  const float* wk      = (const float*)d_in[9];
  const float* wv      = (const float*)d_in[10];
  const float* wo      = (const float*)d_in[11];
  const float* phase   = (const float*)d_in[12];
  const float* nb_g    = (const float*)d_in[13];
  const float* nb_b    = (const float*)d_in[14];
  const float* up_w    = (const float*)d_in[15];
  const float* up_b    = (const float*)d_in[16];
  const float* dn_w    = (const float*)d_in[17];
  const float* dn_b    = (const float*)d_in[18];
  const float* cmt_w   = (const float*)d_in[19];
  const float* cmt_b   = (const float*)d_in[20];
  const float* cproj_w = (const float*)d_in[21];
  const float* cproj_b = (const float*)d_in[22];
  const float* bcast_w = (const float*)d_in[23];
  const float* bcast_b = (const float*)d_in[24];

  char* ws = (char*)d_ws;
  float*  x1     = (float*)(ws + OFF_X1);
  bfbits* h      = (bfbits*)(ws + OFF_H);
  bfbits* h2     = (bfbits*)(ws + OFF_H);     // alias: h dead after QKV
  bfbits* qb     = (bfbits*)(ws + OFF_Q);
  bfbits* kb     = (bfbits*)(ws + OFF_K);
  bfbits* vt     = (bfbits*)(ws + OFF_VT);
  bfbits* ffmid  = (bfbits*)(ws + OFF_Q);     // alias: Q/K dead after attention
  bfbits* ao     = (bfbits*)(ws + OFF_AO);
  float*  x2     = (float*)(ws + OFF_X2);
  float*  pO     = (float*)(ws + OFF_X2);     // alias: x2 written after merge
  bfbits* wqkv_t = (bfbits*)(ws + OFF_WQKV);
  bfbits* wo_t   = (bfbits*)(ws + OFF_WO);
  bfbits* wup_t  = (bfbits*)(ws + OFF_WUP);
  bfbits* wdn_t  = (bfbits*)(ws + OFF_WDN);
  float*  bvec   = (float*)(ws + OFF_BVEC);
  float*  cbv    = (float*)(ws + OFF_CBV);
  float*  gate   = (float*)(ws + OFF_GATE);
  float*  part   = (float*)(ws + OFF_PART);
  float*  pool   = (float*)(ws + OFF_POOL);
  float*  cmt    = (float*)(ws + OFF_CMT);
  float*  pm     = (float*)(ws + OFF_PM);
  float*  pl     = (float*)(ws + OFF_PL);

  float* outx   = (float*)d_out;
  float* outc   = outx + NELEM_X;          // center [B][DC]
  float* outg   = outc + B_ * DC_;         // gate [B][T]
  float* outcmt = outg + B_ * T_;          // commit [B]

  // weight prep (B^T bf16)
  transpose_w<<<dim3(32, 32), 256, 0, stream>>>(wq, wqkv_t,                1024, 1024, 1024, 1024);
  transpose_w<<<dim3(32, 32), 256, 0, stream>>>(wk, wqkv_t + 1024 * 1024,  1024, 1024, 1024, 1024);
  transpose_w<<<dim3(32, 32), 256, 0, stream>>>(wv, wqkv_t + 2048 * 1024,  1024, 1024, 1024, 1024);
  transpose_w<<<dim3(32, 32), 256, 0, stream>>>(wo, wo_t,                  1024, 1024, 1024, 1024);
  transpose_w<<<dim3(32, 52), 256, 0, stream>>>(up_w, wup_t,               1024, DFF_, 1024, DFFP_);
  transpose_w<<<dim3(52, 32), 256, 0, stream>>>(dn_w, wdn_t,               DFF_, 1024, DFFP_, 1024);

  gemv_t<<<dim3(32, B_), 256, 0, stream>>>(cfa, bcast_w, bcast_b, bvec, 0);
  cb_kernel<<<B_, 256, 0, stream>>>(cfa, cb_w, cbv);

  ln1_kernel<<<MTOT, 256, 0, stream>>>(x, bvec, cbv, gate_w, gate_b, nf_g, nf_b,
                                       x1, h, gate, outg);

  gemm_bt<0, 128, 32><<<dim3(24, 32), 256, 0, stream>>>(
      h, 1024, wqkv_t, 1024, 1024, gate, phase, nullptr,
      nullptr, nullptr, qb, kb, vt);

  attn_kernel<<<1536, 128, 0, stream>>>(qb, kb, vt, ao, pm, pl, pO);
  attn_merge<<<512, 64, 0, stream>>>(pm, pl, pO, ao);

  gemm_bt<1, 64, 64><<<dim3(8, 64), 256, 0, stream>>>(
      ao, 1024, wo_t, 1024, 1024, gate, nullptr, nullptr,
      x2, x1, nullptr, nullptr, nullptr);

  ln2_kernel<<<MTOT, 256, 0, stream>>>(x2, nb_g, nb_b, h2);

  // pooled stats only need x2 -> run before FF so DN can fuse the final add
  pool_part<<<dim3(64, B_), 256, 0, stream>>>(x2, part);
  pool_fin<<<8, 256, 0, stream>>>(part, pool);
  commit_kernel<<<B_, 256, 0, stream>>>(pool, cmt_w, cmt_b, cmt, outcmt);
  gemv_t<<<dim3(32, B_), 256, 0, stream>>>(pool, cproj_w, cproj_b, outc, 1);

  gemm_bt<2, 64, 64><<<dim3(13, 64), 256, 0, stream>>>(
      h2, 1024, wup_t, 1024, 1024, up_b, nullptr, nullptr,
      nullptr, nullptr, ffmid, nullptr, nullptr);

  gemm_bt<3, 64, 64><<<dim3(8, 64), 256, 0, stream>>>(
      ffmid, DFFP_, wdn_t, DFFP_, DFFP_, dn_b, gate, cmt,
      outx, x2, nullptr, nullptr, nullptr);
}

// Round 9
// 229.523 us; speedup vs baseline: 1.1868x; 1.0394x over previous
//
#include <hip/hip_runtime.h>
#include <math.h>

// ---- problem constants ----
#define B_   2
#define T_   2048
#define D_   1024
#define H_   16
#define DH_  64
#define DC_  1024
#define DFF_ 1656
#define DFFP_ 1664
#define MTOT 4096          // B_*T_
#define NELEM_X 4194304ull // B*T*D

typedef short s16x8 __attribute__((ext_vector_type(8)));
typedef unsigned short u16x4 __attribute__((ext_vector_type(4)));
typedef float f32x4 __attribute__((ext_vector_type(4)));
typedef float f32x16 __attribute__((ext_vector_type(16)));
typedef unsigned short bfbits;

__device__ __forceinline__ bfbits f2bf(float f) {
  unsigned int u = __builtin_bit_cast(unsigned int, f);
  u += 0x7fffu + ((u >> 16) & 1u);          // RNE
  return (bfbits)(u >> 16);
}

__device__ __forceinline__ float vexp2(float x) {   // 2^x via HW transcendental
  float r;
  asm("v_exp_f32 %0, %1" : "=v"(r) : "v"(x));
  return r;
}
__device__ __forceinline__ unsigned pkbf(float lo, float hi) { // 2xbf16 pack, RNE
  unsigned r;
  asm("v_cvt_pk_bf16_f32 %0, %1, %2" : "=v"(r) : "v"(lo), "v"(hi));
  return r;
}

__device__ __forceinline__ void gload16(const void* g, void* l) {
  __builtin_amdgcn_global_load_lds(
      (__attribute__((address_space(1))) void*)g,
      (__attribute__((address_space(3))) void*)l, 16, 0, 0);
}

// ---------- workspace offsets (bytes) ----------
constexpr size_t OFF_X1   = 0;                                  // f32 x1
constexpr size_t OFF_H    = OFF_X1 + 4ull*NELEM_X;              // bf16 h ; later h2
constexpr size_t OFF_Q    = OFF_H  + 2ull*NELEM_X;              // bf16 Q [BH][T][64] ; later ffmid
constexpr size_t OFF_K    = OFF_Q  + 2ull*NELEM_X;              // bf16 K [BH][T][64]
constexpr size_t OFF_VT   = OFF_K  + 2ull*NELEM_X;              // bf16 V^T [BH][64][T]
constexpr size_t OFF_AO   = OFF_VT + 2ull*NELEM_X;              // bf16 attn out [M][D]
constexpr size_t OFF_X2   = OFF_AO + 2ull*NELEM_X;              // f32 x2; pO alias during attn
constexpr size_t OFF_WQKV = OFF_X2 + 4ull*NELEM_X;              // bf16 [3072][1024]
constexpr size_t OFF_WO   = OFF_WQKV + 3072ull*1024*2;          // bf16 [1024][1024]
constexpr size_t OFF_WUP  = OFF_WO   + 1024ull*1024*2;          // bf16 [1664][1024]
constexpr size_t OFF_WDN  = OFF_WUP  + 1664ull*1024*2;          // bf16 [1024][1664]
constexpr size_t OFF_BVEC = OFF_WDN  + 1024ull*1664*2;          // f32 [B][D]
constexpr size_t OFF_CBV  = OFF_BVEC + 2048ull*4;               // f32 [B]
constexpr size_t OFF_GATE = OFF_CBV  + 256;                     // f32 [M]
constexpr size_t OFF_PART = OFF_GATE + 4096ull*4;               // f32 [128][1024]
constexpr size_t OFF_POOL = OFF_PART + 128ull*1024*4;           // f32 [B][D]
constexpr size_t OFF_CMT  = OFF_POOL + 2048ull*4;               // f32 [B]
constexpr size_t OFF_PM   = OFF_CMT  + 256;                     // f32 [1024][64]
constexpr size_t OFF_PL   = OFF_PM   + 1024ull*64*4;            // f32 [1024][64]

// attention job table: 8 groups (j) x 6 slots; entry = qt | kind<<8
// kind: 0 = full (L), 1 = k-range [0,mid) (A), 2 = k-range [mid,nk) (B)
// every group's 6 jobs sum to exactly 66 k-tiles; max job = 16 tiles.
__constant__ unsigned short JOBS[8][6] = {
  {0x00F, 0x11C, 0x11A, 0x118, 0x006, 0x000},
  {0x11E, 0x11D, 0x11B, 0x119, 0x005, 0x001},
  {0x11F, 0x21D, 0x21B, 0x219, 0x004, 0x002},
  {0x21F, 0x21C, 0x00B, 0x114, 0x008, 0x003},
  {0x21E, 0x00C, 0x116, 0x009, 0x007, 0x210},
  {0x00E, 0x117, 0x217, 0x110, 0x111, 0x211},
  {0x00D, 0x218, 0x115, 0x112, 0x213, 0x212},
  {0x21A, 0x215, 0x216, 0x00A, 0x113, 0x214},
};

// ---------- transpose f32 [R][C] -> bf16 [Npad][Rpad]
__global__ __launch_bounds__(256)
void transpose_w(const float* __restrict__ src, bfbits* __restrict__ dst,
                 int R, int C, int Rpad, int Npad) {
  __shared__ float tile[32][33];
  const int kb = blockIdx.x * 32, nb = blockIdx.y * 32;
  const int tx = threadIdx.x & 31, ty = threadIdx.x >> 5;
  for (int i = ty; i < 32; i += 8) {
    const int k = kb + i, n = nb + tx;
    tile[i][tx] = (k < R && n < C) ? src[(size_t)k * C + n] : 0.f;
  }
  __syncthreads();
  for (int i = ty; i < 32; i += 8) {
    const int n = nb + i, k = kb + tx;
    if (n < Npad && k < Rpad) dst[(size_t)n * Rpad + k] = f2bf(tile[tx][i]);
  }
}

// ---------- GEMV: out[b][d] = f(vec[b] @ w[.][d] + bias[d])
__global__ __launch_bounds__(256)
void gemv_t(const float* __restrict__ v, const float* __restrict__ w,
            const float* __restrict__ bias, float* __restrict__ out,
            int tanh_mode) {
  const int b = blockIdx.y;
  const int dl = threadIdx.x & 31, cl = threadIdx.x >> 5;
  const int d = blockIdx.x * 32 + dl;
  const float* vb = v + b * 1024;
  float s = 0.f;
  #pragma unroll 4
  for (int c = cl; c < 1024; c += 8)
    s += vb[c] * w[(size_t)c * 1024 + d];
  __shared__ float red[8][32];
  red[cl][dl] = s;
  __syncthreads();
  if (threadIdx.x < 32) {
    float t = 0.f;
    #pragma unroll
    for (int i = 0; i < 8; ++i) t += red[i][threadIdx.x];
    const int dd = blockIdx.x * 32 + threadIdx.x;
    t += bias[dd];
    out[b * 1024 + dd] = tanh_mode ? tanhf(t) : t;
  }
}

__global__ __launch_bounds__(256)
void cb_kernel(const float* __restrict__ cfa, const float* __restrict__ cbw,
               float* __restrict__ cbv) {
  const int b = blockIdx.x, tid = threadIdx.x;
  float4 a = *(const float4*)(cfa + b * 1024 + tid * 4);
  float4 w = *(const float4*)(cbw + tid * 4);
  float s = a.x * w.x + a.y * w.y + a.z * w.z + a.w * w.w;
  #pragma unroll
  for (int o = 32; o > 0; o >>= 1) s += __shfl_xor(s, o);
  __shared__ float ls[4];
  if ((tid & 63) == 0) ls[tid >> 6] = s;
  __syncthreads();
  if (tid == 0) cbv[b] = ls[0] + ls[1] + ls[2] + ls[3];
}

__device__ __forceinline__ void blockreduce3(float& a, float& b, float& c) {
  #pragma unroll
  for (int o = 32; o > 0; o >>= 1) {
    a += __shfl_xor(a, o);
    b += __shfl_xor(b, o);
    c += __shfl_xor(c, o);
  }
  __shared__ float ls[3][4];
  const int lane = threadIdx.x & 63, w = threadIdx.x >> 6;
  if (lane == 0) { ls[0][w] = a; ls[1][w] = b; ls[2][w] = c; }
  __syncthreads();
  a = ls[0][0] + ls[0][1] + ls[0][2] + ls[0][3];
  b = ls[1][0] + ls[1][1] + ls[1][2] + ls[1][3];
  c = ls[2][0] + ls[2][1] + ls[2][2] + ls[2][3];
}

// ---------- fused: x1 = x + bvec ; gate ; LN(x1) -> h (bf16)
__global__ __launch_bounds__(256)
void ln1_kernel(const float* __restrict__ x, const float* __restrict__ bvec,
                const float* __restrict__ cbv, const float* __restrict__ gw,
                const float* __restrict__ gb, const float* __restrict__ nfg,
                const float* __restrict__ nfb, float* __restrict__ x1,
                bfbits* __restrict__ h, float* __restrict__ gate_ws,
                float* __restrict__ gate_out) {
  const int m = blockIdx.x, tid = threadIdx.x, b = m >> 11;
  const size_t ro = (size_t)m * D_ + tid * 4;
  float4 xv = *(const float4*)(x + ro);
  float4 bv = *(const float4*)(bvec + b * D_ + tid * 4);
  float4 v;
  v.x = xv.x + bv.x; v.y = xv.y + bv.y; v.z = xv.z + bv.z; v.w = xv.w + bv.w;
  float4 g4 = *(const float4*)(gw + tid * 4);
  float s  = v.x + v.y + v.z + v.w;
  float s2 = v.x*v.x + v.y*v.y + v.z*v.z + v.w*v.w;
  float dg = v.x*g4.x + v.y*g4.y + v.z*g4.z + v.w*g4.w;
  blockreduce3(s, s2, dg);
  const float mean = s * (1.0f/1024.0f);
  const float var  = s2 * (1.0f/1024.0f) - mean*mean;
  const float rstd = rsqrtf(var + 1e-5f);
  if (tid == 0) {
    const float logits = dg + gb[0] + cbv[b];
    const float prob = 1.0f / (1.0f + expf(-logits));
    const float hard = prob > 0.5f ? 1.0f : 0.0f;
    const float gv = (hard - prob) + prob;
    gate_ws[m] = gv; gate_out[m] = gv;
  }
  *(float4*)(x1 + ro) = v;
  float4 gg = *(const float4*)(nfg + tid * 4);
  float4 b2 = *(const float4*)(nfb + tid * 4);
  u16x4 hv;
  hv[0] = f2bf((v.x - mean) * rstd * gg.x + b2.x);
  hv[1] = f2bf((v.y - mean) * rstd * gg.y + b2.y);
  hv[2] = f2bf((v.z - mean) * rstd * gg.z + b2.z);
  hv[3] = f2bf((v.w - mean) * rstd * gg.w + b2.w);
  *(u16x4*)(h + ro) = hv;
}

__global__ __launch_bounds__(256)
void ln2_kernel(const float* __restrict__ x2, const float* __restrict__ gptr,
                const float* __restrict__ bptr, bfbits* __restrict__ h2) {
  const int m = blockIdx.x, tid = threadIdx.x;
  const size_t ro = (size_t)m * D_ + tid * 4;
  float4 v = *(const float4*)(x2 + ro);
  float s  = v.x + v.y + v.z + v.w;
  float s2 = v.x*v.x + v.y*v.y + v.z*v.z + v.w*v.w;
  float d0 = 0.f;
  blockreduce3(s, s2, d0);
  const float mean = s * (1.0f/1024.0f);
  const float var  = s2 * (1.0f/1024.0f) - mean*mean;
  const float rstd = rsqrtf(var + 1e-5f);
  float4 gg = *(const float4*)(gptr + tid * 4);
  float4 b2 = *(const float4*)(bptr + tid * 4);
  u16x4 hv;
  hv[0] = f2bf((v.x - mean) * rstd * gg.x + b2.x);
  hv[1] = f2bf((v.y - mean) * rstd * gg.y + b2.y);
  hv[2] = f2bf((v.z - mean) * rstd * gg.z + b2.z);
  hv[3] = f2bf((v.w - mean) * rstd * gg.w + b2.w);
  *(u16x4*)(h2 + ro) = hv;
}

// ---------- GEMM: C[M][N] = A[M][K](bf16) * Bt[N][K](bf16), double-buffered LDS,
// XOR-swizzled staging (source-side) so ds_read_b128 is ~conflict-free.
// 4 waves as 2x2; wave tile (BM/2) x (BN/2).
// EPI 0: QKV (rope+gate, Q*(1/8)*log2e; V -> V^T)  [BM=128, BK=32, BN=128]
// EPI 1: WO (x2 = x1 + C*gate)                      [64, 64, 64]
// EPI 2: UP (gelu(C+up_b) -> bf16, ldc=1664)        [64, 64, 64]
// EPI 3: DN fused final (outx = x2+cmt*gate*(C+b))  [64, 64, 64]
template <int EPI, int BM, int BK, int BN>
__global__ void __launch_bounds__(256, 2)
gemm_bt(const bfbits* __restrict__ A, int lda,
        const bfbits* __restrict__ Bt, int ldb, int K,
        const float* __restrict__ p0, const float* __restrict__ p1,
        const float* __restrict__ p2,
        float* __restrict__ fo0, const float* __restrict__ fo1,
        bfbits* __restrict__ bo0, bfbits* __restrict__ bo1,
        bfbits* __restrict__ bo2) {
  constexpr int MI = BM / 32;               // m-fragments per wave
  constexpr int NJ = BN / 32;               // n-fragments per wave
  constexpr int RCH = BK / 8;               // 16B chunks per row
  constexpr int NK = BK / 32;               // 32-wide k sub-steps
  __shared__ bfbits Asl[2][BM * BK];
  __shared__ bfbits Bsl[2][BN * BK];
  const int tid = threadIdx.x;
  const int lane = tid & 63, wave = tid >> 6;
  const int g = lane >> 4, l15 = lane & 15;
  const int wr = wave >> 1, wc = wave & 1;
  const int m0 = blockIdx.y * BM, n0 = blockIdx.x * BN;

  auto stage = [&](int k0, int p) {
    #pragma unroll
    for (int i = 0; i < (BM * RCH) / 256; ++i) {
      const int c = i * 256 + tid;
      const int row = c / RCH;
      const int ko = ((c % RCH) ^ (row & (RCH - 1))) * 8;
      gload16(A + (size_t)(m0 + row) * lda + (k0 + ko),
              (char*)&Asl[p][0] + c * 16);
    }
    #pragma unroll
    for (int i = 0; i < (BN * RCH) / 256; ++i) {
      const int c = i * 256 + tid;
      const int row = c / RCH;
      const int ko = ((c % RCH) ^ (row & (RCH - 1))) * 8;
      gload16(Bt + (size_t)(n0 + row) * ldb + (k0 + ko),
              (char*)&Bsl[p][0] + c * 16);
    }
  };

  f32x4 acc[MI][NJ] = {};
  stage(0, 0);
  __syncthreads();

  int t = 0;
  for (int k0 = 0; k0 < K; k0 += BK, ++t) {
    const int p = t & 1;
    if (k0 + BK < K) stage(k0 + BK, p ^ 1);
    s16x8 af[NK][MI], bfr[NK][NJ];
    #pragma unroll
    for (int kk = 0; kk < NK; ++kk) {
      #pragma unroll
      for (int i = 0; i < MI; ++i) {
        const int row = wr * (MI * 16) + i * 16 + l15;
        af[kk][i] = *(const s16x8*)&Asl[p][row * BK + (((kk * 4 + g) ^ (row & (RCH - 1))) * 8)];
      }
      #pragma unroll
      for (int i = 0; i < NJ; ++i) {
        const int row = wc * (NJ * 16) + i * 16 + l15;
        bfr[kk][i] = *(const s16x8*)&Bsl[p][row * BK + (((kk * 4 + g) ^ (row & (RCH - 1))) * 8)];
      }
    }
    #pragma unroll
    for (int kk = 0; kk < NK; ++kk)
      #pragma unroll
      for (int i = 0; i < MI; ++i)
        #pragma unroll
        for (int j = 0; j < NJ; ++j)
          acc[i][j] = __builtin_amdgcn_mfma_f32_16x16x32_bf16(af[kk][i], bfr[kk][j], acc[i][j], 0, 0, 0);
    __syncthreads();
  }

  const int b = m0 >> 11;
  const int trow0 = (m0 & 2047) + wr * (MI * 16);

  if constexpr (EPI == 0) {
    const float* gate = p0;
    const float* phase = p1;
    const int ncol0 = n0 + wc * 64;
    const int section = ncol0 >> 10;          // 0=Q 1=K 2=V
    const int hh = (ncol0 & 1023) >> 6;
    if (section == 2) {
      bfbits* vt = bo2;
      const size_t vhead = (size_t)(b * H_ + hh) * DH_ * T_;
      #pragma unroll
      for (int mi = 0; mi < MI; ++mi) {
        const int tb = trow0 + mi * 16 + g * 4;
        #pragma unroll
        for (int ni = 0; ni < NJ; ++ni) {
          const int dh = ni * 16 + l15;
          unsigned* dst32 = (unsigned*)&vt[vhead + (size_t)dh * T_ + tb];
          dst32[0] = pkbf(acc[mi][ni][0], acc[mi][ni][1]);
          dst32[1] = pkbf(acc[mi][ni][2], acc[mi][ni][3]);
        }
      }
    } else {
      const float cc = cosf(phase[hh]);
      const float ssn = sinf(phase[hh]);
      // Q carries 1/sqrt(DH) and log2(e): scores land in exp2 domain.
      const float qs = (section == 0) ? 0.125f * 1.44269504088896341f : 1.0f;
      bfbits* dst = (section == 0) ? bo0 : bo1;
      const size_t head = (size_t)(b * H_ + hh) * T_ * DH_;
      #pragma unroll
      for (int mi = 0; mi < MI; ++mi) {
        const int tb = trow0 + mi * 16 + g * 4;
        float gv[4];
        #pragma unroll
        for (int r = 0; r < 4; ++r) gv[r] = gate[(size_t)b * T_ + tb + r] * qs;
        #pragma unroll
        for (int ni = 0; ni < 2; ++ni) {
          const int dh = ni * 16 + l15;
          #pragma unroll
          for (int r = 0; r < 4; ++r) {
            const float re = acc[mi][ni][r];
            const float im = acc[mi][ni + 2][r];
            const size_t idx = head + (size_t)(tb + r) * DH_ + dh;
            dst[idx]      = f2bf((re * cc - im * ssn) * gv[r]);
            dst[idx + 32] = f2bf((re * ssn + im * cc) * gv[r]);
          }
        }
      }
    }
  } else if constexpr (EPI == 1) {
    const float* gate = p0;
    const float* x1 = fo1;
    float* x2 = fo0;
    #pragma unroll
    for (int mi = 0; mi < MI; ++mi) {
      const int m = m0 + wr * (MI * 16) + mi * 16 + g * 4;
      float gv[4];
      #pragma unroll
      for (int r = 0; r < 4; ++r) gv[r] = gate[m + r];
      #pragma unroll
      for (int ni = 0; ni < NJ; ++ni) {
        const int n = n0 + wc * (NJ * 16) + ni * 16 + l15;
        #pragma unroll
        for (int r = 0; r < 4; ++r) {
          const size_t idx = (size_t)(m + r) * D_ + n;
          x2[idx] = x1[idx] + acc[mi][ni][r] * gv[r];
        }
      }
    }
  } else if constexpr (EPI == 2) {
    const float* upb = p0;
    bfbits* outm = bo0;
    #pragma unroll
    for (int mi = 0; mi < MI; ++mi) {
      const int m = m0 + wr * (MI * 16) + mi * 16 + g * 4;
      #pragma unroll
      for (int ni = 0; ni < NJ; ++ni) {
        const int n = n0 + wc * (NJ * 16) + ni * 16 + l15;
        const float bb = upb[n < DFF_ ? n : DFF_ - 1];
        #pragma unroll
        for (int r = 0; r < 4; ++r) {
          float v = acc[mi][ni][r] + bb;
          v = 0.5f * v * (1.0f + erff(v * 0.70710678118654752f));
          outm[(size_t)(m + r) * DFFP_ + n] = f2bf(v);
        }
      }
    }
  } else {
    const float* dnb = p0;
    const float* gate = p1;
    const float* cmt = p2;
    const float* x2 = fo1;
    float* outx = fo0;
    const float cb = cmt[b];
    #pragma unroll
    for (int mi = 0; mi < MI; ++mi) {
      const int m = m0 + wr * (MI * 16) + mi * 16 + g * 4;
      float kv[4];
      #pragma unroll
      for (int r = 0; r < 4; ++r) kv[r] = cb * gate[m + r];
      #pragma unroll
      for (int ni = 0; ni < NJ; ++ni) {
        const int n = n0 + wc * (NJ * 16) + ni * 16 + l15;
        const float bb = dnb[n];
        #pragma unroll
        for (int r = 0; r < 4; ++r) {
          const size_t idx = (size_t)(m + r) * D_ + n;
          outx[idx] = x2[idx] + kv[r] * (acc[mi][ni][r] + bb);
        }
      }
    }
  }
}

// ---------- flash attention v8: split-K jobs, all equal-length per CU.
// 1536 blocks x 2 waves; wave owns 32 q-rows; KVBLK=64; single-buffer LDS
// (16KB -> 6 blocks/CU co-resident = 12 waves/CU). Heavy q-tiles (qt>=16)
// split into two k-range partial jobs (m,l,O^T f32 partials), merged after.
__global__ void __launch_bounds__(128, 3)
attn_kernel(const bfbits* __restrict__ Qb, const bfbits* __restrict__ Kb,
            const bfbits* __restrict__ Vt, bfbits* __restrict__ AO,
            float* __restrict__ pm, float* __restrict__ pl,
            float* __restrict__ pO) {
  __shared__ bfbits Kl[64 * 64];   // [k row][dh], chunk-swizzled
  __shared__ bfbits Vl[64 * 64];   // [dh row][k], chunk-swizzled
  const int pid = blockIdx.x;         // 0..1535
  const int bh = pid & 31;
  const int j = (pid >> 5) & 7;
  const int slot = pid >> 8;          // 0..5
  const unsigned job = JOBS[j][slot];
  const int qt = job & 0xFF;
  const int kind = job >> 8;          // 0=L 1=A 2=B
  const int nk = qt + 1;
  const int mid = (nk + 1) >> 1;
  const int t0 = (kind == 2) ? mid : 0;
  const int t1 = (kind == 1) ? mid : nk;
  const int qb0 = qt * 64;
  const int tid = threadIdx.x, lane = tid & 63, wq = tid >> 6;
  const int l31 = lane & 31, hi = lane >> 5;
  const int qw = qb0 + wq * 32;       // wave q base

  const bfbits* Qp = Qb + ((size_t)bh * T_ + qw) * DH_;
  const bfbits* Kp = Kb + (size_t)bh * T_ * DH_;
  const bfbits* Vp = Vt + (size_t)bh * DH_ * T_;

  // Q fragments (B-operand): lane l -> Q[qw + l31][mf*16 + hi*8 + e]
  s16x8 qf[4];
  #pragma unroll
  for (int mf = 0; mf < 4; ++mf)
    qf[mf] = *(const s16x8*)(Qp + l31 * DH_ + mf * 16 + hi * 8);

  f32x16 o0 = {}, o1 = {};            // O^T[dh][q], dh-halves 0..31 / 32..63
  float mrun = -INFINITY, lrun = 0.f;

  // staging: chunk c = i*128+tid; row=c>>3; src col chunk = (c&7)^(row&7)
  const bfbits* kg[4];
  const bfbits* vg[4];
  int cb_[4];
  #pragma unroll
  for (int i = 0; i < 4; ++i) {
    const int c = i * 128 + tid;
    const int row = c >> 3;
    const int sc = ((c & 7) ^ (row & 7)) * 8;
    kg[i] = Kp + row * DH_ + sc;
    vg[i] = Vp + (size_t)row * T_ + sc;
    cb_[i] = c * 16;
  }

  for (int t = t0; t < t1; ++t) {
    const int k0 = t << 6;
    #pragma unroll
    for (int i = 0; i < 4; ++i) {
      gload16(kg[i] + (size_t)k0 * DH_, (char*)&Kl[0] + cb_[i]);
      gload16(vg[i] + k0,               (char*)&Vl[0] + cb_[i]);
    }
    __syncthreads();                  // drains vmcnt -> tiles ready
    // ---- QK^T: S^T[64k][32q], two 32x32 halves ----
    f32x16 s0 = {}, s1 = {};
    __builtin_amdgcn_s_setprio(1);
    #pragma unroll
    for (int mf = 0; mf < 4; ++mf) {
      const int ch = ((mf * 2 + hi) ^ (l31 & 7)) * 8;
      const s16x8 ka  = *(const s16x8*)&Kl[l31 * 64 + ch];
      const s16x8 kb2 = *(const s16x8*)&Kl[(32 + l31) * 64 + ch];
      s0 = __builtin_amdgcn_mfma_f32_32x32x16_bf16(ka,  qf[mf], s0, 0, 0, 0);
      s1 = __builtin_amdgcn_mfma_f32_32x32x16_bf16(kb2, qf[mf], s1, 0, 0, 0);
    }
    __builtin_amdgcn_s_setprio(0);
    // ---- causal mask (only the diagonal tile t == qt) ----
    if (t == qt) {
      const int qd = wq * 32 + l31;       // q - k0
      #pragma unroll
      for (int r = 0; r < 16; ++r) {
        const int krow = (r & 3) + 8 * (r >> 2) + 4 * hi;
        if (krow > qd)      s0[r] = -1e9f;
        if (krow + 32 > qd) s1[r] = -1e9f;
      }
    }
    // ---- online softmax (exp2 domain), in-lane tree + 1 shfl ----
    float red[8];
    #pragma unroll
    for (int i = 0; i < 8; ++i)
      red[i] = fmaxf(fmaxf(s0[i], s0[i + 8]), fmaxf(s1[i], s1[i + 8]));
    #pragma unroll
    for (int i = 0; i < 4; ++i) red[i] = fmaxf(red[i], red[i + 4]);
    float mx = fmaxf(fmaxf(red[0], red[1]), fmaxf(red[2], red[3]));
    mx = fmaxf(mx, __shfl_xor(mx, 32));
    const bool need = __any(mx > mrun + 8.f) != 0;   // defer-max
    const float mnew = need ? fmaxf(mrun, mx) : mrun;
    s0 = s0 - mnew;
    s1 = s1 - mnew;
    #pragma unroll
    for (int i = 0; i < 16; ++i) { s0[i] = vexp2(s0[i]); s1[i] = vexp2(s1[i]); }
    float sr[8];
    #pragma unroll
    for (int i = 0; i < 8; ++i)
      sr[i] = (s0[i] + s0[i + 8]) + (s1[i] + s1[i + 8]);
    #pragma unroll
    for (int i = 0; i < 4; ++i) sr[i] += sr[i + 4];
    float sum = (sr[0] + sr[1]) + (sr[2] + sr[3]);
    sum += __shfl_xor(sum, 32);
    if (need) {
      const float alpha = vexp2(mrun - mnew);
      mrun = mnew;
      lrun = lrun * alpha + sum;
      o0 *= alpha;
      o1 *= alpha;
    } else {
      lrun += sum;
    }
    // ---- pack P subtiles + PV (O^T += V^T * P^T) ----
    #pragma unroll
    for (int mf = 0; mf < 4; ++mf) {
      const f32x16& s = (mf < 2) ? s0 : s1;
      const int r0 = (mf & 1) * 8;
      const unsigned A0 = pkbf(s[r0 + 0], s[r0 + 1]);
      const unsigned A1 = pkbf(s[r0 + 2], s[r0 + 3]);
      const unsigned B0 = pkbf(s[r0 + 4], s[r0 + 5]);
      const unsigned B1 = pkbf(s[r0 + 6], s[r0 + 7]);
      const unsigned x0 = (unsigned)__shfl_xor((int)(hi ? A0 : B0), 32);
      const unsigned x1 = (unsigned)__shfl_xor((int)(hi ? A1 : B1), 32);
      uint4 wv;
      wv.x = hi ? x0 : A0;
      wv.y = hi ? x1 : A1;
      wv.z = hi ? B0 : x0;
      wv.w = hi ? B1 : x1;
      const s16x8 pf = __builtin_bit_cast(s16x8, wv);
      const int ch = ((mf * 2 + hi) ^ (l31 & 7)) * 8;
      const s16x8 v0 = *(const s16x8*)&Vl[l31 * 64 + ch];
      const s16x8 v1 = *(const s16x8*)&Vl[(32 + l31) * 64 + ch];
      __builtin_amdgcn_s_setprio(1);
      o0 = __builtin_amdgcn_mfma_f32_32x32x16_bf16(v0, pf, o0, 0, 0, 0);
      o1 = __builtin_amdgcn_mfma_f32_32x32x16_bf16(v1, pf, o1, 0, 0, 0);
      __builtin_amdgcn_s_setprio(0);
    }
    __syncthreads();                  // all reads done before next overwrite
  }

  if (kind == 0) {
    // ---- direct epilogue: reg r -> dh = (r&3)+8*(r>>2)+4*hi, col q = l31 ----
    const float inv = 1.0f / lrun;
    const int q = qw + l31;
    bfbits* dst = AO + ((size_t)(bh >> 4) * T_ + q) * D_ + (bh & 15) * DH_;
    #pragma unroll
    for (int rp = 0; rp < 8; ++rp) {
      const int dh = ((2 * rp) & 3) + 8 * (rp >> 1) + 4 * hi;
      *(unsigned*)(dst + dh)      = pkbf(o0[2 * rp] * inv, o0[2 * rp + 1] * inv);
      *(unsigned*)(dst + 32 + dh) = pkbf(o1[2 * rp] * inv, o1[2 * rp + 1] * inv);
    }
  } else {
    // ---- partial epilogue: store m, l, unnormalized O^T (f32) ----
    const int jid = ((qt - 16) * 32 + bh) * 2 + (kind - 1);
    const int qloc = wq * 32 + l31;
    pm[jid * 64 + qloc] = mrun;
    pl[jid * 64 + qloc] = lrun;
    float* po = pO + (size_t)jid * 4096;
    #pragma unroll
    for (int r = 0; r < 16; ++r) {
      const int dh = (r & 3) + 8 * (r >> 2) + 4 * hi;
      po[dh * 64 + qloc]        = o0[r];
      po[(dh + 32) * 64 + qloc] = o1[r];
    }
  }
}

// ---------- merge split-K attention partials (qt 16..31) ----------
__global__ void __launch_bounds__(64)
attn_merge(const float* __restrict__ pm, const float* __restrict__ pl,
           const float* __restrict__ pO, bfbits* __restrict__ AO) {
  __shared__ float lds[64][65];
  const int u = blockIdx.x;             // 0..511
  const int qt = 16 + (u >> 5), bh = u & 31;
  const int q = threadIdx.x;            // 0..63
  const int jA = ((qt - 16) * 32 + bh) * 2, jB = jA + 1;
  const float mA = pm[jA * 64 + q], mB = pm[jB * 64 + q];
  const float lA = pl[jA * 64 + q], lB = pl[jB * 64 + q];
  const float m = fmaxf(mA, mB);
  const float eA = vexp2(mA - m), eB = vexp2(mB - m);
  const float inv = 1.0f / (lA * eA + lB * eB);
  const float* OA = pO + (size_t)jA * 4096;
  const float* OB = pO + (size_t)jB * 4096;
  for (int dh = 0; dh < 64; ++dh)
    lds[dh][q] = (OA[dh * 64 + q] * eA + OB[dh * 64 + q] * eB) * inv;
  __syncthreads();
  const int b = bh >> 4, hh = bh & 15;
  bfbits* dst = AO + ((size_t)b * T_ + qt * 64) * D_ + hh * DH_ + q; // thread=dh col
  for (int qq = 0; qq < 64; ++qq)
    dst[(size_t)qq * D_] = f2bf(lds[q][qq]);
}

// ---------- pooling / commit ----------
__global__ __launch_bounds__(256)
void pool_part(const float* __restrict__ x2, float* __restrict__ part) {
  const int s = blockIdx.x, b = blockIdx.y, tid = threadIdx.x;
  const float* base = x2 + ((size_t)b * T_ + s * 32) * D_ + tid * 4;
  float ax = 0, ay = 0, az = 0, aw = 0;
  #pragma unroll 4
  for (int t = 0; t < 32; ++t) {
    float4 v = *(const float4*)(base + (size_t)t * D_);
    ax += v.x; ay += v.y; az += v.z; aw += v.w;
  }
  float4 ov; ov.x = ax; ov.y = ay; ov.z = az; ov.w = aw;
  *(float4*)(part + (size_t)(b * 64 + s) * D_ + tid * 4) = ov;
}

__global__ __launch_bounds__(256)
void pool_fin(const float* __restrict__ part, float* __restrict__ pool) {
  const int idx = blockIdx.x * 256 + threadIdx.x; // 0..2047
  const int b = idx >> 10, d = idx & 1023;
  float s = 0.f;
  #pragma unroll 8
  for (int i = 0; i < 64; ++i) s += part[(size_t)(b * 64 + i) * D_ + d];
  pool[idx] = s * (1.0f / 2048.0f);
}

__global__ __launch_bounds__(256)
void commit_kernel(const float* __restrict__ pool, const float* __restrict__ cw,
                   const float* __restrict__ cb0, float* __restrict__ cmt,
                   float* __restrict__ out_cmt) {
  const int b = blockIdx.x, tid = threadIdx.x;
  float4 p = *(const float4*)(pool + b * 1024 + tid * 4);
  float4 w = *(const float4*)(cw + tid * 4);
  float s = p.x * w.x + p.y * w.y + p.z * w.z + p.w * w.w;
  #pragma unroll
  for (int o = 32; o > 0; o >>= 1) s += __shfl_xor(s, o);
  __shared__ float ls[4];
  if ((tid & 63) == 0) ls[tid >> 6] = s;
  __syncthreads();
  if (tid == 0) {
    const float t = ls[0] + ls[1] + ls[2] + ls[3] + cb0[0];
    const float v = 1.0f / (1.0f + expf(-t));
    cmt[b] = v; out_cmt[b] = v;
  }
}

// ---------------- host launcher ----------------
extern "C" void kernel_launch(void* const* d_in, const int* in_sizes, int n_in,
                              void* d_out, int out_size, void* d_ws, size_t ws_size,
                              hipStream_t stream) {
  (void)in_sizes; (void)n_in; (void)out_size; (void)ws_size;
  const float* x       = (const float*)d_in[0];
  const float* cfa     = (const float*)d_in[1];
  const float* gate_w  = (const float*)d_in[3];
  const float* gate_b  = (const float*)d_in[4];
  const float* cb_w    = (const float*)d_in[5];
  const float* nf_g    = (const float*)d_in[6];
  const float* nf_b    = (const float*)d_in[7];
  const float* wq      = (const float*)d_in[8];
  const float* wk      = (const float*)d_in[9];
  const float* wv      = (const float*)d_in[10];
  const float* wo      = (const float*)d_in[11];
  const float* phase   = (const float*)d_in[12];
  const float* nb_g    = (const float*)d_in[13];
  const float* nb_b    = (const float*)d_in[14];
  const float* up_w    = (const float*)d_in[15];
  const float* up_b    = (const float*)d_in[16];
  const float* dn_w    = (const float*)d_in[17];
  const float* dn_b    = (const float*)d_in[18];
  const float* cmt_w   = (const float*)d_in[19];
  const float* cmt_b   = (const float*)d_in[20];
  const float* cproj_w = (const float*)d_in[21];
  const float* cproj_b = (const float*)d_in[22];
  const float* bcast_w = (const float*)d_in[23];
  const float* bcast_b = (const float*)d_in[24];

  char* ws = (char*)d_ws;
  float*  x1     = (float*)(ws + OFF_X1);
  bfbits* h      = (bfbits*)(ws + OFF_H);
  bfbits* h2     = (bfbits*)(ws + OFF_H);     // alias: h dead after QKV
  bfbits* qb     = (bfbits*)(ws + OFF_Q);
  bfbits* kb     = (bfbits*)(ws + OFF_K);
  bfbits* vt     = (bfbits*)(ws + OFF_VT);
  bfbits* ffmid  = (bfbits*)(ws + OFF_Q);     // alias: Q/K dead after attention
  bfbits* ao     = (bfbits*)(ws + OFF_AO);
  float*  x2     = (float*)(ws + OFF_X2);
  float*  pO     = (float*)(ws + OFF_X2);     // alias: x2 written after merge
  bfbits* wqkv_t = (bfbits*)(ws + OFF_WQKV);
  bfbits* wo_t   = (bfbits*)(ws + OFF_WO);
  bfbits* wup_t  = (bfbits*)(ws + OFF_WUP);
  bfbits* wdn_t  = (bfbits*)(ws + OFF_WDN);
  float*  bvec   = (float*)(ws + OFF_BVEC);
  float*  cbv    = (float*)(ws + OFF_CBV);
  float*  gate   = (float*)(ws + OFF_GATE);
  float*  part   = (float*)(ws + OFF_PART);
  float*  pool   = (float*)(ws + OFF_POOL);
  float*  cmt    = (float*)(ws + OFF_CMT);
  float*  pm     = (float*)(ws + OFF_PM);
  float*  pl     = (float*)(ws + OFF_PL);

  float* outx   = (float*)d_out;
  float* outc   = outx + NELEM_X;          // center [B][DC]
  float* outg   = outc + B_ * DC_;         // gate [B][T]
  float* outcmt = outg + B_ * T_;          // commit [B]

  // weight prep (B^T bf16)
  transpose_w<<<dim3(32, 32), 256, 0, stream>>>(wq, wqkv_t,                1024, 1024, 1024, 1024);
  transpose_w<<<dim3(32, 32), 256, 0, stream>>>(wk, wqkv_t + 1024 * 1024,  1024, 1024, 1024, 1024);
  transpose_w<<<dim3(32, 32), 256, 0, stream>>>(wv, wqkv_t + 2048 * 1024,  1024, 1024, 1024, 1024);
  transpose_w<<<dim3(32, 32), 256, 0, stream>>>(wo, wo_t,                  1024, 1024, 1024, 1024);
  transpose_w<<<dim3(32, 52), 256, 0, stream>>>(up_w, wup_t,               1024, DFF_, 1024, DFFP_);
  transpose_w<<<dim3(52, 32), 256, 0, stream>>>(dn_w, wdn_t,               DFF_, 1024, DFFP_, 1024);

  gemv_t<<<dim3(32, B_), 256, 0, stream>>>(cfa, bcast_w, bcast_b, bvec, 0);
  cb_kernel<<<B_, 256, 0, stream>>>(cfa, cb_w, cbv);

  ln1_kernel<<<MTOT, 256, 0, stream>>>(x, bvec, cbv, gate_w, gate_b, nf_g, nf_b,
                                       x1, h, gate, outg);

  gemm_bt<0, 128, 32, 128><<<dim3(24, 32), 256, 0, stream>>>(
      h, 1024, wqkv_t, 1024, 1024, gate, phase, nullptr,
      nullptr, nullptr, qb, kb, vt);

  attn_kernel<<<1536, 128, 0, stream>>>(qb, kb, vt, ao, pm, pl, pO);
  attn_merge<<<512, 64, 0, stream>>>(pm, pl, pO, ao);

  gemm_bt<1, 64, 64, 64><<<dim3(16, 64), 256, 0, stream>>>(
      ao, 1024, wo_t, 1024, 1024, gate, nullptr, nullptr,
      x2, x1, nullptr, nullptr, nullptr);

  ln2_kernel<<<MTOT, 256, 0, stream>>>(x2, nb_g, nb_b, h2);

  // pooled stats only need x2 -> run before FF so DN can fuse the final add
  pool_part<<<dim3(64, B_), 256, 0, stream>>>(x2, part);
  pool_fin<<<8, 256, 0, stream>>>(part, pool);
  commit_kernel<<<B_, 256, 0, stream>>>(pool, cmt_w, cmt_b, cmt, outcmt);
  gemv_t<<<dim3(32, B_), 256, 0, stream>>>(pool, cproj_w, cproj_b, outc, 1);

  gemm_bt<2, 64, 64, 64><<<dim3(26, 64), 256, 0, stream>>>(
      h2, 1024, wup_t, 1024, 1024, up_b, nullptr, nullptr,
      nullptr, nullptr, ffmid, nullptr, nullptr);

  gemm_bt<3, 64, 64, 64><<<dim3(16, 64), 256, 0, stream>>>(
      ffmid, DFFP_, wdn_t, DFFP_, DFFP_, dn_b, gate, cmt,
      outx, x2, nullptr, nullptr, nullptr);
}